// Round 3
// baseline (1916.673 us; speedup 1.0000x reference)
//
#include <hip/hip_runtime.h>
#include <stdint.h>

#define N_T 32768
#define N_Q 4096
#define E_T 1048576
#define E_Q 131072
#define H   128
#define NL  3

typedef float  f32x4  __attribute__((ext_vector_type(4)));
typedef short  s16x8  __attribute__((ext_vector_type(8)));

// ---------------- utility kernels ----------------
__global__ void zero_i32_k(int* p, int n){
  int i = blockIdx.x*blockDim.x + threadIdx.x;
  if(i<n) p[i]=0;
}
__global__ void zero_f32_k(float* p, int n){
  int i = blockIdx.x*blockDim.x + threadIdx.x;
  if(i<n) p[i]=0.f;
}

// classify mask dtype: flag bit0 -> uint8 bools, bit1 -> float32, 0 -> int32
__global__ void detect_mask_k(const unsigned* m, int* flag){
  int t = threadIdx.x;
  int f = 0;
  for(int j=t;j<4096;j+=256){
    unsigned v = m[j];
    if(v > 1u) f |= (v & 0xFEFEFEFEu) ? 2 : 1;
  }
  if(f) atomicOr(flag, f);
}

// ---------------- CSR build ----------------
__global__ void count_k(const int* __restrict__ dst, int E, int* cnt){
  int i = blockIdx.x*blockDim.x + threadIdx.x;
  if(i<E) atomicAdd(&cnt[dst[i]], 1);
}

__global__ void scan_k(const int* __restrict__ cnt, int n, int* rp, int* pos){
  __shared__ int part[1024];
  int t = threadIdx.x;
  int chunk = (n + 1023) >> 10;
  int lo = t*chunk, hi = lo+chunk; if(hi>n) hi=n;
  int s = 0;
  for(int i=lo;i<hi;i++) s += cnt[i];
  part[t] = s;
  __syncthreads();
  for(int off=1; off<1024; off<<=1){
    int v = (t >= off) ? part[t-off] : 0;
    __syncthreads();
    part[t] += v;
    __syncthreads();
  }
  int run = (t==0) ? 0 : part[t-1];
  for(int i=lo;i<hi;i++){ rp[i]=run; pos[i]=run; run += cnt[i]; }
  if(t==0) rp[n] = part[1023];
}

__global__ void fill_k(const int* __restrict__ src, const int* __restrict__ dst,
                       int E, int* pos, int* csr){
  int i = blockIdx.x*blockDim.x + threadIdx.x;
  if(i<E){
    int p = atomicAdd(&pos[dst[i]], 1);
    csr[p] = src[i];
  }
}

// ---------------- embedding gather ----------------
__global__ void embed_k(const int* __restrict__ idx, const float* __restrict__ emb,
                        float* __restrict__ out, int N){
  int i = blockIdx.x*blockDim.x + threadIdx.x;   // N*32 threads
  int n = i >> 5, c = i & 31;
  if(n < N){
    ((float4*)out)[(size_t)n*32 + c] = ((const float4*)emb)[(size_t)idx[n]*32 + c];
  }
}

// ---------------- segment mean (one wave per dst node) ----------------
__global__ void agg_k(const float* __restrict__ x, const int* __restrict__ rp,
                      const int* __restrict__ csr, float* __restrict__ agg, int N){
  int wid = (int)(((size_t)blockIdx.x*blockDim.x + threadIdx.x) >> 6);
  int lane = threadIdx.x & 63;
  if(wid >= N) return;
  int rs = rp[wid], re = rp[wid+1];
  float ax=0.f, ay=0.f;
  for(int j=rs;j<re;j++){
    int s = csr[j];
    float2 v = ((const float2*)x)[(size_t)s*64 + lane];
    ax += v.x; ay += v.y;
  }
  int c = re - rs; if(c < 1) c = 1;
  float inv = 1.0f / (float)c;
  float2 o; o.x = ax*inv; o.y = ay*inv;
  ((float2*)agg)[(size_t)wid*64 + lane] = o;
}

// bf16 hi/lo split
__device__ inline void bf16_split(float x, ushort& hi, ushort& lo){
  union { float f; unsigned u; } v; v.f = x;
  unsigned r = (v.u + 0x7FFFu + ((v.u >> 16) & 1u)) & 0xFFFF0000u;
  hi = (ushort)(r >> 16);
  union { unsigned u; float f; } h; h.u = r;
  float rem = x - h.f;
  union { float f; unsigned u; } w; w.f = rem;
  unsigned r2 = (w.u + 0x7FFFu + ((w.u >> 16) & 1u)) & 0xFFFF0000u;
  lo = (ushort)(r2 >> 16);
}

// ---------------- layer GEMM: out = elu(agg@Wl.T + bl + x@Wr.T) ----------------
__global__ __launch_bounds__(256,1) void layer_k(
    const float* __restrict__ agg, const float* __restrict__ x,
    const float* __restrict__ Wl, const float* __restrict__ Wr,
    const float* __restrict__ bl, float* __restrict__ outf,
    ushort* __restrict__ outHi, ushort* __restrict__ outLo,
    int N, int last){
  __shared__ float WT[128*128];
  __shared__ float AT[128*128];
  int t = threadIdx.x;
  int r0g = blockIdx.x * 128;
  int rg = t & 15, cg = t >> 4;
  int r0 = rg*8, c0 = cg*8;
  float acc[8][8] = {};
  for(int ph=0; ph<2; ph++){
    const float* W = ph ? Wr : Wl;
    const float* A = ph ? x : agg;
    if(ph) __syncthreads();
    #pragma unroll
    for(int i=0;i<16;i++){
      int lin = t + i*256;            // 0..4095
      int c = lin & 127, kg = lin >> 7;
      float4 w = *(const float4*)&W[(size_t)c*H + kg*4];
      WT[(kg*4+0)*128 + c] = w.x;
      WT[(kg*4+1)*128 + c] = w.y;
      WT[(kg*4+2)*128 + c] = w.z;
      WT[(kg*4+3)*128 + c] = w.w;
      float4 a = *(const float4*)&A[(size_t)(r0g + c)*H + kg*4];
      AT[(kg*4+0)*128 + c] = a.x;
      AT[(kg*4+1)*128 + c] = a.y;
      AT[(kg*4+2)*128 + c] = a.z;
      AT[(kg*4+3)*128 + c] = a.w;
    }
    __syncthreads();
    for(int k=0;k<128;k++){
      float4 a0 = *(float4*)&AT[k*128 + r0];
      float4 a1 = *(float4*)&AT[k*128 + r0+4];
      float4 w0 = *(float4*)&WT[k*128 + c0];
      float4 w1 = *(float4*)&WT[k*128 + c0+4];
      float av[8] = {a0.x,a0.y,a0.z,a0.w,a1.x,a1.y,a1.z,a1.w};
      float wv[8] = {w0.x,w0.y,w0.z,w0.w,w1.x,w1.y,w1.z,w1.w};
      #pragma unroll
      for(int rr=0;rr<8;rr++)
        #pragma unroll
        for(int cc=0;cc<8;cc++)
          acc[rr][cc] += av[rr]*wv[cc];
    }
  }
  #pragma unroll
  for(int rr=0;rr<8;rr++)
    #pragma unroll
    for(int cc=0;cc<8;cc++){
      float v = acc[rr][cc] + bl[c0+cc];
      acc[rr][cc] = (v > 0.f) ? v : expm1f(v);
    }
  if(!last){
    #pragma unroll
    for(int rr=0;rr<8;rr++){
      float4 v0; v0.x=acc[rr][0]; v0.y=acc[rr][1]; v0.z=acc[rr][2]; v0.w=acc[rr][3];
      float4 v1; v1.x=acc[rr][4]; v1.y=acc[rr][5]; v1.z=acc[rr][6]; v1.w=acc[rr][7];
      size_t off = (size_t)(r0g + r0 + rr)*H + c0;
      *(float4*)&outf[off]   = v0;
      *(float4*)&outf[off+4] = v1;
    }
  } else {
    #pragma unroll
    for(int rr=0;rr<8;rr++){
      ushort hh[8], ll[8];
      #pragma unroll
      for(int cc=0;cc<8;cc++) bf16_split(acc[rr][cc], hh[cc], ll[cc]);
      uint4 hv, lv;
      hv.x = (unsigned)hh[0] | ((unsigned)hh[1]<<16);
      hv.y = (unsigned)hh[2] | ((unsigned)hh[3]<<16);
      hv.z = (unsigned)hh[4] | ((unsigned)hh[5]<<16);
      hv.w = (unsigned)hh[6] | ((unsigned)hh[7]<<16);
      lv.x = (unsigned)ll[0] | ((unsigned)ll[1]<<16);
      lv.y = (unsigned)ll[2] | ((unsigned)ll[3]<<16);
      lv.z = (unsigned)ll[4] | ((unsigned)ll[5]<<16);
      lv.w = (unsigned)ll[6] | ((unsigned)ll[7]<<16);
      size_t off = (size_t)(r0g + r0 + rr)*H + c0;
      *(uint4*)&outHi[off] = hv;
      *(uint4*)&outLo[off] = lv;
    }
  }
}

// ---------------- attention helpers ----------------
// stage 128x128 mask tile as packed bits into MB[512] (word = r*4 + col/32)
__device__ __forceinline__ void stage_mask_raw(const void* maskp, int mb,
                                               int gr0, int gc0, unsigned* MB, int t){
  int wv = t >> 6, lane = t & 63;
  #pragma unroll 8
  for(int i=0;i<64;i++){
    int id = i*4 + wv;             // 0..255
    int r = id >> 1, c64 = id & 1;
    size_t off = (size_t)(gr0 + r)*N_T + gc0 + c64*64 + lane;
    bool pred;
    if(mb & 2)      pred = (((const float*)maskp)[off]   != 0.f);
    else if(mb & 1) pred = (((const uint8_t*)maskp)[off] != 0);
    else            pred = (((const int*)maskp)[off]     != 0);
    unsigned long long b = __ballot(pred);
    if(lane == 0){
      MB[r*4 + c64*2]     = (unsigned)b;
      MB[r*4 + c64*2 + 1] = (unsigned)(b >> 32);
    }
  }
}

// shared hi/lo bf16 QK^T GEMM core: 128x128 tile, 4 waves (2x2), 64x64/wave
__device__ __forceinline__ void qk_gemm(
    const ushort* __restrict__ eqHi, const ushort* __restrict__ eqLo,
    const ushort* __restrict__ etHi, const ushort* __restrict__ etLo,
    int gr0, int gc0, int t, ushort* SM, f32x4 (&acc)[4][4]){
  ushort* QH = SM;
  ushort* QL = SM + 8192;
  ushort* TH = SM + 16384;
  ushort* TL = SM + 24576;
  int lane = t & 63;
  int w = t >> 6;
  int wr = w >> 1, wc = w & 1;
  int fr = lane & 15, kg0 = lane >> 4;
  for(int kt=0; kt<2; kt++){
    __syncthreads();
    #pragma unroll
    for(int it=0; it<4; it++){
      int idx = t + it*256;          // 0..1023
      int row = idx >> 3, k8 = idx & 7;
      int sw = (k8 ^ (row & 7)) * 8;
      size_t goffQ = (size_t)(gr0 + row)*H + kt*64 + k8*8;
      size_t goffT = (size_t)(gc0 + row)*H + kt*64 + k8*8;
      *(uint4*)&QH[row*64 + sw] = *(const uint4*)&eqHi[goffQ];
      *(uint4*)&QL[row*64 + sw] = *(const uint4*)&eqLo[goffQ];
      *(uint4*)&TH[row*64 + sw] = *(const uint4*)&etHi[goffT];
      *(uint4*)&TL[row*64 + sw] = *(const uint4*)&etLo[goffT];
    }
    __syncthreads();
    #pragma unroll
    for(int s=0; s<2; s++){
      int kg = s*4 + kg0;
      s16x8 ah[4], al[4], bh[4], bl_[4];
      #pragma unroll
      for(int m=0;m<4;m++){
        int ar = wr*64 + m*16 + fr;
        int ia = ar*64 + ((kg ^ (ar & 7)) << 3);
        ah[m] = *(const s16x8*)&QH[ia];
        al[m] = *(const s16x8*)&QL[ia];
      }
      #pragma unroll
      for(int n=0;n<4;n++){
        int bc = wc*64 + n*16 + fr;
        int ib = bc*64 + ((kg ^ (bc & 7)) << 3);
        bh[n] = *(const s16x8*)&TH[ib];
        bl_[n] = *(const s16x8*)&TL[ib];
      }
      #pragma unroll
      for(int m=0;m<4;m++)
        #pragma unroll
        for(int n=0;n<4;n++){
          acc[m][n] = __builtin_amdgcn_mfma_f32_16x16x32_bf16(ah[m], bh[n],  acc[m][n], 0,0,0);
          acc[m][n] = __builtin_amdgcn_mfma_f32_16x16x32_bf16(ah[m], bl_[n], acc[m][n], 0,0,0);
          acc[m][n] = __builtin_amdgcn_mfma_f32_16x16x32_bf16(al[m], bh[n],  acc[m][n], 0,0,0);
        }
    }
  }
}

// ---------------- attention pass A: rowsums (+ optional packed-bit emit) ----------------
__global__ __launch_bounds__(256,2) void attsum_k(
    const ushort* __restrict__ eqHi, const ushort* __restrict__ eqLo,
    const ushort* __restrict__ etHi, const ushort* __restrict__ etLo,
    const void* __restrict__ maskp, const int* __restrict__ flag,
    float* __restrict__ rowsum, unsigned* __restrict__ bitsOut){
  __shared__ ushort SM[4*128*64];
  __shared__ __align__(16) unsigned MB[512];
  int t = threadIdx.x;
  int gc0 = blockIdx.x * 128;
  int gr0 = blockIdx.y * 128;
  int lane = t & 63;
  int w = t >> 6;
  int wr = w >> 1, wc = w & 1;
  int fr = lane & 15, kg0 = lane >> 4;

  int mb = *flag;
  stage_mask_raw(maskp, mb, gr0, gc0, MB, t);
  __syncthreads();
  if(bitsOut && t < 128){
    *(uint4*)&bitsOut[(size_t)(gr0 + t)*(N_T/32) + (gc0 >> 5)] = *(uint4*)&MB[t*4];
  }

  f32x4 acc[4][4] = {};
  qk_gemm(eqHi, eqLo, etHi, etLo, gr0, gc0, t, SM, acc);

  const float sc = 0.08838834764831845f;   // 1/sqrt(128)
  #pragma unroll
  for(int m=0;m<4;m++){
    #pragma unroll
    for(int reg=0;reg<4;reg++){
      int l = wr*64 + m*16 + kg0*4 + reg;
      unsigned w0 = MB[l*4 + wc*2];
      unsigned w1 = MB[l*4 + wc*2 + 1];
      float s = 0.f;
      float p;
      p = ((w0 >> fr)      & 1u) ? __expf(acc[m][0][reg]*sc) : 0.f; s += p;
      p = ((w0 >> (fr+16)) & 1u) ? __expf(acc[m][1][reg]*sc) : 0.f; s += p;
      p = ((w1 >> fr)      & 1u) ? __expf(acc[m][2][reg]*sc) : 0.f; s += p;
      p = ((w1 >> (fr+16)) & 1u) ? __expf(acc[m][3][reg]*sc) : 0.f; s += p;
      s += __shfl_xor(s, 1);
      s += __shfl_xor(s, 2);
      s += __shfl_xor(s, 4);
      s += __shfl_xor(s, 8);
      if(fr == 0) atomicAdd(&rowsum[gr0 + l], s);
    }
  }
}

// ---------------- attention pass B: recompute, normalize, coalesced store ----------------
__global__ __launch_bounds__(256,2) void attout_k(
    const ushort* __restrict__ eqHi, const ushort* __restrict__ eqLo,
    const ushort* __restrict__ etHi, const ushort* __restrict__ etLo,
    const void* __restrict__ maskp, const int* __restrict__ flag,
    const unsigned* __restrict__ bitsIn, const float* __restrict__ rowsum,
    float* __restrict__ out){
  __shared__ float PT[128*132];            // 67.6 KB; low 64 KB aliased as staging
  __shared__ __align__(16) unsigned MB[512];
  __shared__ float IRS[128];
  ushort* SM = (ushort*)PT;
  int t = threadIdx.x;
  int gc0 = blockIdx.x * 128;
  int gr0 = blockIdx.y * 128;
  int lane = t & 63;
  int w = t >> 6;
  int wr = w >> 1, wc = w & 1;
  int fr = lane & 15, kg0 = lane >> 4;

  if(bitsIn){
    if(t < 128)
      *(uint4*)&MB[t*4] = *(const uint4*)&bitsIn[(size_t)(gr0 + t)*(N_T/32) + (gc0 >> 5)];
  } else {
    int mb = *flag;
    stage_mask_raw(maskp, mb, gr0, gc0, MB, t);
  }
  if(t < 128) IRS[t] = 1.0f / rowsum[gr0 + t];

  f32x4 acc[4][4] = {};
  qk_gemm(eqHi, eqLo, etHi, etLo, gr0, gc0, t, SM, acc);

  __syncthreads();   // all waves done reading SM before PT overwrite

  const float sc = 0.08838834764831845f;
  #pragma unroll
  for(int m=0;m<4;m++){
    #pragma unroll
    for(int reg=0;reg<4;reg++){
      int l = wr*64 + m*16 + kg0*4 + reg;
      unsigned w0 = MB[l*4 + wc*2];
      unsigned w1 = MB[l*4 + wc*2 + 1];
      float ir = IRS[l];
      int cb = wc*64 + fr;
      PT[l*132 + cb     ] = ((w0 >> fr)      & 1u) ? __expf(acc[m][0][reg]*sc)*ir : 0.f;
      PT[l*132 + cb + 16] = ((w0 >> (fr+16)) & 1u) ? __expf(acc[m][1][reg]*sc)*ir : 0.f;
      PT[l*132 + cb + 32] = ((w1 >> fr)      & 1u) ? __expf(acc[m][2][reg]*sc)*ir : 0.f;
      PT[l*132 + cb + 48] = ((w1 >> (fr+16)) & 1u) ? __expf(acc[m][3][reg]*sc)*ir : 0.f;
    }
  }
  __syncthreads();

  // coalesced float4 store of the 128x128 tile
  #pragma unroll
  for(int i=0;i<16;i++){
    int idx = t + i*256;               // 0..4095
    int row = idx >> 5, c4 = idx & 31;
    f32x4 v = *(const f32x4*)&PT[row*132 + c4*4];
    float4 o; o.x=v[0]; o.y=v[1]; o.z=v[2]; o.w=v[3];
    *(float4*)&out[(size_t)(gr0 + row)*N_T + gc0 + c4*4] = o;
  }
}

// ---------------- host launch ----------------
extern "C" void kernel_launch(void* const* d_in, const int* in_sizes, int n_in,
                              void* d_out, int out_size, void* d_ws, size_t ws_size,
                              hipStream_t stream){
  const int* tx  = (const int*)d_in[0];
  const int* qx  = (const int*)d_in[1];
  const int* te  = (const int*)d_in[2];
  const int* qe  = (const int*)d_in[3];
  const void* mask = d_in[4];
  const float* emb = (const float*)d_in[5];
  const float* Wl  = (const float*)d_in[6];
  const float* bl  = (const float*)d_in[7];
  const float* Wr  = (const float*)d_in[8];
  float* out = (float*)d_out;

  // ws layout: features bf16 hi/lo + rowsum + flag (+ optional bit-mask at 19MB)
  ushort* etHi = (ushort*)d_ws;                       // N_T*H
  ushort* etLo = etHi + (size_t)N_T*H;
  ushort* eqHi = etLo + (size_t)N_T*H;                // N_Q*H
  ushort* eqLo = eqHi + (size_t)N_Q*H;
  float* rowsum = (float*)(eqLo + (size_t)N_Q*H);
  int*   flag   = (int*)(rowsum + N_Q);
  bool useBits = ws_size >= ((size_t)37 << 20);
  unsigned* bits = useBits ? (unsigned*)((char*)d_ws + ((size_t)19 << 20)) : nullptr;

  // phase-1 scratch lives inside d_out (512MB; overwritten by attout afterwards)
  float* S    = out;
  float* xt0  = S;
  float* xt1  = S + 4194304;
  float* aggt = S + 8388608;
  float* xq0  = S + 12582912;
  float* xq1  = xq0 + 524288;
  float* aggq = xq1 + 524288;
  int*   ib    = (int*)(aggq + 524288);
  int*   cnt_t = ib;
  int*   rp_t  = cnt_t + N_T;
  int*   pos_t = rp_t + N_T + 1;
  int*   csr_t = pos_t + N_T;
  int*   cnt_q = csr_t + E_T;
  int*   rp_q  = cnt_q + N_Q;
  int*   pos_q = rp_q + N_Q + 1;
  int*   csr_q = pos_q + N_Q;

  zero_i32_k<<<(N_T+255)/256,256,0,stream>>>(cnt_t, N_T);
  zero_i32_k<<<(N_Q+255)/256,256,0,stream>>>(cnt_q, N_Q);
  zero_f32_k<<<(N_Q+255)/256,256,0,stream>>>(rowsum, N_Q);
  zero_i32_k<<<1,256,0,stream>>>(flag, 1);
  detect_mask_k<<<1,256,0,stream>>>((const unsigned*)mask, flag);

  count_k<<<E_T/256,256,0,stream>>>(te+E_T, E_T, cnt_t);
  scan_k<<<1,1024,0,stream>>>(cnt_t, N_T, rp_t, pos_t);
  fill_k<<<E_T/256,256,0,stream>>>(te, te+E_T, E_T, pos_t, csr_t);
  count_k<<<E_Q/256,256,0,stream>>>(qe+E_Q, E_Q, cnt_q);
  scan_k<<<1,1024,0,stream>>>(cnt_q, N_Q, rp_q, pos_q);
  fill_k<<<E_Q/256,256,0,stream>>>(qe, qe+E_Q, E_Q, pos_q, csr_q);

  embed_k<<<N_T*32/256,256,0,stream>>>(tx, emb, xt0, N_T);
  embed_k<<<N_Q*32/256,256,0,stream>>>(qx, emb, xq0, N_Q);

  float* ct = xt0; float* nt = xt1;
  float* cq = xq0; float* nq = xq1;
  for(int l=0;l<NL;l++){
    int last = (l == NL-1);
    agg_k<<<N_T/4,256,0,stream>>>(ct, rp_t, csr_t, aggt, N_T);
    layer_k<<<N_T/128,256,0,stream>>>(aggt, ct, Wl+(size_t)l*H*H, Wr+(size_t)l*H*H,
                                      bl+(size_t)l*H, nt, etHi, etLo, N_T, last);
    agg_k<<<N_Q/4,256,0,stream>>>(cq, rp_q, csr_q, aggq, N_Q);
    layer_k<<<N_Q/128,256,0,stream>>>(aggq, cq, Wl+(size_t)l*H*H, Wr+(size_t)l*H*H,
                                      bl+(size_t)l*H, nq, eqHi, eqLo, N_Q, last);
    float* tmp;
    tmp = ct; ct = nt; nt = tmp;
    tmp = cq; cq = nq; nq = tmp;
  }

  attsum_k<<<dim3(N_T/128, N_Q/128),256,0,stream>>>(eqHi, eqLo, etHi, etLo,
                                                    mask, flag, rowsum, bits);
  attout_k<<<dim3(N_T/128, N_Q/128),256,0,stream>>>(eqHi, eqLo, etHi, etLo,
                                                    mask, flag, bits, rowsum, out);
}

// Round 4
// 1390.467 us; speedup vs baseline: 1.3784x; 1.3784x over previous
//
#include <hip/hip_runtime.h>
#include <stdint.h>

#define N_T 32768
#define N_Q 4096
#define E_T 1048576
#define E_Q 131072
#define H   128
#define NL  3

typedef float  f32x4  __attribute__((ext_vector_type(4)));
typedef short  s16x8  __attribute__((ext_vector_type(8)));

// ---------------- utility kernels ----------------
__global__ void zero_i32_k(int* p, int n){
  int i = blockIdx.x*blockDim.x + threadIdx.x;
  if(i<n) p[i]=0;
}
__global__ void zero_f32_k(float* p, int n){
  int i = blockIdx.x*blockDim.x + threadIdx.x;
  if(i<n) p[i]=0.f;
}

// classify mask dtype: flag bit0 -> uint8 bools, bit1 -> float32, 0 -> int32
__global__ void detect_mask_k(const unsigned* m, int* flag){
  int t = threadIdx.x;
  int f = 0;
  for(int j=t;j<4096;j+=256){
    unsigned v = m[j];
    if(v > 1u) f |= (v & 0xFEFEFEFEu) ? 2 : 1;
  }
  if(f) atomicOr(flag, f);
}

// ---------------- mask -> packed bits (streaming, BW-bound) ----------------
// one block per query row; row = 32768 cols = 1024 words; LDS nibble staging
__device__ __forceinline__ unsigned nib8(unsigned x, unsigned y){
  unsigned r = (x & 0xFu) | ((x>>4)&0xF0u) | ((x>>8)&0xF00u) | ((x>>12)&0xF000u);
  unsigned s = (y & 0xFu) | ((y>>4)&0xF0u) | ((y>>8)&0xF00u) | ((y>>12)&0xF000u);
  return r | (s<<16);
}

__global__ __launch_bounds__(256) void pack_mask_k(
    const void* __restrict__ maskp, const int* __restrict__ flag,
    unsigned* __restrict__ bits){
  __shared__ uint8_t NB[8192];          // one nibble-byte per float4 group
  int t = threadIdx.x;
  int r = blockIdx.x;
  int mb = *flag;
  size_t rbase = (size_t)r * N_T;
  if(mb & 2){
    const float* mp = (const float*)maskp + rbase;
    #pragma unroll 4
    for(int i=0;i<32;i++){
      float4 v = *(const float4*)&mp[i*1024 + t*4];
      unsigned nib = (v.x!=0.f) | ((v.y!=0.f)<<1) | ((v.z!=0.f)<<2) | ((v.w!=0.f)<<3);
      NB[i*256 + t] = (uint8_t)nib;
    }
  } else if(mb & 1){
    const uint8_t* mp = (const uint8_t*)maskp + rbase;
    #pragma unroll 4
    for(int i=0;i<32;i++){
      uchar4 v = *(const uchar4*)&mp[i*1024 + t*4];
      unsigned nib = (v.x!=0) | ((v.y!=0)<<1) | ((v.z!=0)<<2) | ((v.w!=0)<<3);
      NB[i*256 + t] = (uint8_t)nib;
    }
  } else {
    const int* mp = (const int*)maskp + rbase;
    #pragma unroll 4
    for(int i=0;i<32;i++){
      int4 v = *(const int4*)&mp[i*1024 + t*4];
      unsigned nib = (v.x!=0) | ((v.y!=0)<<1) | ((v.z!=0)<<2) | ((v.w!=0)<<3);
      NB[i*256 + t] = (uint8_t)nib;
    }
  }
  __syncthreads();
  uint4 a = *(const uint4*)&NB[32*t];
  uint4 b = *(const uint4*)&NB[32*t + 16];
  uint4 o;
  o.x = nib8(a.x, a.y);
  o.y = nib8(a.z, a.w);
  o.z = nib8(b.x, b.y);
  o.w = nib8(b.z, b.w);
  *(uint4*)&bits[(size_t)r*(N_T/32) + 4*t] = o;
}

// ---------------- CSR build ----------------
__global__ void count_k(const int* __restrict__ dst, int E, int* cnt){
  int i = blockIdx.x*blockDim.x + threadIdx.x;
  if(i<E) atomicAdd(&cnt[dst[i]], 1);
}

__global__ void scan_k(const int* __restrict__ cnt, int n, int* rp, int* pos){
  __shared__ int part[1024];
  int t = threadIdx.x;
  int chunk = (n + 1023) >> 10;
  int lo = t*chunk, hi = lo+chunk; if(hi>n) hi=n;
  int s = 0;
  for(int i=lo;i<hi;i++) s += cnt[i];
  part[t] = s;
  __syncthreads();
  for(int off=1; off<1024; off<<=1){
    int v = (t >= off) ? part[t-off] : 0;
    __syncthreads();
    part[t] += v;
    __syncthreads();
  }
  int run = (t==0) ? 0 : part[t-1];
  for(int i=lo;i<hi;i++){ rp[i]=run; pos[i]=run; run += cnt[i]; }
  if(t==0) rp[n] = part[1023];
}

__global__ void fill_k(const int* __restrict__ src, const int* __restrict__ dst,
                       int E, int* pos, int* csr){
  int i = blockIdx.x*blockDim.x + threadIdx.x;
  if(i<E){
    int p = atomicAdd(&pos[dst[i]], 1);
    csr[p] = src[i];
  }
}

// ---------------- embedding gather ----------------
__global__ void embed_k(const int* __restrict__ idx, const float* __restrict__ emb,
                        float* __restrict__ out, int N){
  int i = blockIdx.x*blockDim.x + threadIdx.x;   // N*32 threads
  int n = i >> 5, c = i & 31;
  if(n < N){
    ((float4*)out)[(size_t)n*32 + c] = ((const float4*)emb)[(size_t)idx[n]*32 + c];
  }
}

// ---------------- segment mean (one wave per dst node, 4 rows in flight) ----------------
__global__ void agg_k(const float* __restrict__ x, const int* __restrict__ rp,
                      const int* __restrict__ csr, float* __restrict__ agg, int N){
  int wid = (int)(((size_t)blockIdx.x*blockDim.x + threadIdx.x) >> 6);
  int lane = threadIdx.x & 63;
  if(wid >= N) return;
  int rs = rp[wid], re = rp[wid+1];
  float ax=0.f, ay=0.f, bx=0.f, by=0.f, cx=0.f, cy=0.f, dx=0.f, dy=0.f;
  int j = rs;
  for(; j+4 <= re; j+=4){
    int s0 = csr[j], s1 = csr[j+1], s2 = csr[j+2], s3 = csr[j+3];
    float2 v0 = ((const float2*)x)[(size_t)s0*64 + lane];
    float2 v1 = ((const float2*)x)[(size_t)s1*64 + lane];
    float2 v2 = ((const float2*)x)[(size_t)s2*64 + lane];
    float2 v3 = ((const float2*)x)[(size_t)s3*64 + lane];
    ax += v0.x; ay += v0.y;
    bx += v1.x; by += v1.y;
    cx += v2.x; cy += v2.y;
    dx += v3.x; dy += v3.y;
  }
  for(; j < re; j++){
    int s = csr[j];
    float2 v = ((const float2*)x)[(size_t)s*64 + lane];
    ax += v.x; ay += v.y;
  }
  float sx = (ax + bx) + (cx + dx);
  float sy = (ay + by) + (cy + dy);
  int c = re - rs; if(c < 1) c = 1;
  float inv = 1.0f / (float)c;
  float2 o; o.x = sx*inv; o.y = sy*inv;
  ((float2*)agg)[(size_t)wid*64 + lane] = o;
}

// bf16 hi/lo split
__device__ inline void bf16_split(float x, ushort& hi, ushort& lo){
  union { float f; unsigned u; } v; v.f = x;
  unsigned r = (v.u + 0x7FFFu + ((v.u >> 16) & 1u)) & 0xFFFF0000u;
  hi = (ushort)(r >> 16);
  union { unsigned u; float f; } h; h.u = r;
  float rem = x - h.f;
  union { float f; unsigned u; } w; w.f = rem;
  unsigned r2 = (w.u + 0x7FFFu + ((w.u >> 16) & 1u)) & 0xFFFF0000u;
  lo = (ushort)(r2 >> 16);
}

// ---------------- layer GEMM: out = elu(agg@Wl.T + bl + x@Wr.T) ----------------
__global__ __launch_bounds__(256,1) void layer_k(
    const float* __restrict__ agg, const float* __restrict__ x,
    const float* __restrict__ Wl, const float* __restrict__ Wr,
    const float* __restrict__ bl, float* __restrict__ outf,
    ushort* __restrict__ outHi, ushort* __restrict__ outLo,
    int N, int last){
  __shared__ float WT[128*128];
  __shared__ float AT[128*128];
  int t = threadIdx.x;
  int r0g = blockIdx.x * 128;
  int rg = t & 15, cg = t >> 4;
  int r0 = rg*8, c0 = cg*8;
  float acc[8][8] = {};
  for(int ph=0; ph<2; ph++){
    const float* W = ph ? Wr : Wl;
    const float* A = ph ? x : agg;
    if(ph) __syncthreads();
    #pragma unroll
    for(int i=0;i<16;i++){
      int lin = t + i*256;            // 0..4095
      int c = lin & 127, kg = lin >> 7;
      float4 w = *(const float4*)&W[(size_t)c*H + kg*4];
      WT[(kg*4+0)*128 + c] = w.x;
      WT[(kg*4+1)*128 + c] = w.y;
      WT[(kg*4+2)*128 + c] = w.z;
      WT[(kg*4+3)*128 + c] = w.w;
      float4 a = *(const float4*)&A[(size_t)(r0g + c)*H + kg*4];
      AT[(kg*4+0)*128 + c] = a.x;
      AT[(kg*4+1)*128 + c] = a.y;
      AT[(kg*4+2)*128 + c] = a.z;
      AT[(kg*4+3)*128 + c] = a.w;
    }
    __syncthreads();
    for(int k=0;k<128;k++){
      float4 a0 = *(float4*)&AT[k*128 + r0];
      float4 a1 = *(float4*)&AT[k*128 + r0+4];
      float4 w0 = *(float4*)&WT[k*128 + c0];
      float4 w1 = *(float4*)&WT[k*128 + c0+4];
      float av[8] = {a0.x,a0.y,a0.z,a0.w,a1.x,a1.y,a1.z,a1.w};
      float wv[8] = {w0.x,w0.y,w0.z,w0.w,w1.x,w1.y,w1.z,w1.w};
      #pragma unroll
      for(int rr=0;rr<8;rr++)
        #pragma unroll
        for(int cc=0;cc<8;cc++)
          acc[rr][cc] += av[rr]*wv[cc];
    }
  }
  #pragma unroll
  for(int rr=0;rr<8;rr++)
    #pragma unroll
    for(int cc=0;cc<8;cc++){
      float v = acc[rr][cc] + bl[c0+cc];
      acc[rr][cc] = (v > 0.f) ? v : expm1f(v);
    }
  if(!last){
    #pragma unroll
    for(int rr=0;rr<8;rr++){
      float4 v0; v0.x=acc[rr][0]; v0.y=acc[rr][1]; v0.z=acc[rr][2]; v0.w=acc[rr][3];
      float4 v1; v1.x=acc[rr][4]; v1.y=acc[rr][5]; v1.z=acc[rr][6]; v1.w=acc[rr][7];
      size_t off = (size_t)(r0g + r0 + rr)*H + c0;
      *(float4*)&outf[off]   = v0;
      *(float4*)&outf[off+4] = v1;
    }
  } else {
    #pragma unroll
    for(int rr=0;rr<8;rr++){
      ushort hh[8], ll[8];
      #pragma unroll
      for(int cc=0;cc<8;cc++) bf16_split(acc[rr][cc], hh[cc], ll[cc]);
      uint4 hv, lv;
      hv.x = (unsigned)hh[0] | ((unsigned)hh[1]<<16);
      hv.y = (unsigned)hh[2] | ((unsigned)hh[3]<<16);
      hv.z = (unsigned)hh[4] | ((unsigned)hh[5]<<16);
      hv.w = (unsigned)hh[6] | ((unsigned)hh[7]<<16);
      lv.x = (unsigned)ll[0] | ((unsigned)ll[1]<<16);
      lv.y = (unsigned)ll[2] | ((unsigned)ll[3]<<16);
      lv.z = (unsigned)ll[4] | ((unsigned)ll[5]<<16);
      lv.w = (unsigned)ll[6] | ((unsigned)ll[7]<<16);
      size_t off = (size_t)(r0g + r0 + rr)*H + c0;
      *(uint4*)&outHi[off] = hv;
      *(uint4*)&outLo[off] = lv;
    }
  }
}

// ---------------- attention helpers ----------------
// fallback: stage 128x128 mask tile as packed bits into MB[512]
__device__ __forceinline__ void stage_mask_raw(const void* maskp, int mb,
                                               int gr0, int gc0, unsigned* MB, int t){
  int wv = t >> 6, lane = t & 63;
  #pragma unroll 8
  for(int i=0;i<64;i++){
    int id = i*4 + wv;             // 0..255
    int r = id >> 1, c64 = id & 1;
    size_t off = (size_t)(gr0 + r)*N_T + gc0 + c64*64 + lane;
    bool pred;
    if(mb & 2)      pred = (((const float*)maskp)[off]   != 0.f);
    else if(mb & 1) pred = (((const uint8_t*)maskp)[off] != 0);
    else            pred = (((const int*)maskp)[off]     != 0);
    unsigned long long b = __ballot(pred);
    if(lane == 0){
      MB[r*4 + c64*2]     = (unsigned)b;
      MB[r*4 + c64*2 + 1] = (unsigned)(b >> 32);
    }
  }
}

// shared hi/lo bf16 QK^T GEMM core: 128x128 tile, 4 waves (2x2), 64x64/wave
__device__ __forceinline__ void qk_gemm(
    const ushort* __restrict__ eqHi, const ushort* __restrict__ eqLo,
    const ushort* __restrict__ etHi, const ushort* __restrict__ etLo,
    int gr0, int gc0, int t, ushort* SM, f32x4 (&acc)[4][4]){
  ushort* QH = SM;
  ushort* QL = SM + 8192;
  ushort* TH = SM + 16384;
  ushort* TL = SM + 24576;
  int lane = t & 63;
  int w = t >> 6;
  int wr = w >> 1, wc = w & 1;
  int fr = lane & 15, kg0 = lane >> 4;
  for(int kt=0; kt<2; kt++){
    __syncthreads();
    #pragma unroll
    for(int it=0; it<4; it++){
      int idx = t + it*256;          // 0..1023
      int row = idx >> 3, k8 = idx & 7;
      int sw = (k8 ^ (row & 7)) * 8;
      size_t goffQ = (size_t)(gr0 + row)*H + kt*64 + k8*8;
      size_t goffT = (size_t)(gc0 + row)*H + kt*64 + k8*8;
      *(uint4*)&QH[row*64 + sw] = *(const uint4*)&eqHi[goffQ];
      *(uint4*)&QL[row*64 + sw] = *(const uint4*)&eqLo[goffQ];
      *(uint4*)&TH[row*64 + sw] = *(const uint4*)&etHi[goffT];
      *(uint4*)&TL[row*64 + sw] = *(const uint4*)&etLo[goffT];
    }
    __syncthreads();
    #pragma unroll
    for(int s=0; s<2; s++){
      int kg = s*4 + kg0;
      s16x8 ah[4], al[4], bh[4], bl_[4];
      #pragma unroll
      for(int m=0;m<4;m++){
        int ar = wr*64 + m*16 + fr;
        int ia = ar*64 + ((kg ^ (ar & 7)) << 3);
        ah[m] = *(const s16x8*)&QH[ia];
        al[m] = *(const s16x8*)&QL[ia];
      }
      #pragma unroll
      for(int n=0;n<4;n++){
        int bc = wc*64 + n*16 + fr;
        int ib = bc*64 + ((kg ^ (bc & 7)) << 3);
        bh[n] = *(const s16x8*)&TH[ib];
        bl_[n] = *(const s16x8*)&TL[ib];
      }
      #pragma unroll
      for(int m=0;m<4;m++)
        #pragma unroll
        for(int n=0;n<4;n++){
          acc[m][n] = __builtin_amdgcn_mfma_f32_16x16x32_bf16(ah[m], bh[n],  acc[m][n], 0,0,0);
          acc[m][n] = __builtin_amdgcn_mfma_f32_16x16x32_bf16(ah[m], bl_[n], acc[m][n], 0,0,0);
          acc[m][n] = __builtin_amdgcn_mfma_f32_16x16x32_bf16(al[m], bh[n],  acc[m][n], 0,0,0);
        }
    }
  }
}

// ---------------- attention pass A: rowsums ----------------
__global__ __launch_bounds__(256,2) void attsum_k(
    const ushort* __restrict__ eqHi, const ushort* __restrict__ eqLo,
    const ushort* __restrict__ etHi, const ushort* __restrict__ etLo,
    const void* __restrict__ maskp, const int* __restrict__ flag,
    const unsigned* __restrict__ bitsIn, float* __restrict__ rowsum){
  __shared__ ushort SM[4*128*64];
  __shared__ __align__(16) unsigned MB[512];
  int t = threadIdx.x;
  int gc0 = blockIdx.x * 128;
  int gr0 = blockIdx.y * 128;
  int lane = t & 63;
  int w = t >> 6;
  int wr = w >> 1, wc = w & 1;
  int fr = lane & 15, kg0 = lane >> 4;

  if(bitsIn){
    if(t < 128)
      *(uint4*)&MB[t*4] = *(const uint4*)&bitsIn[(size_t)(gr0 + t)*(N_T/32) + (gc0 >> 5)];
  } else {
    int mb = *flag;
    stage_mask_raw(maskp, mb, gr0, gc0, MB, t);
  }

  f32x4 acc[4][4] = {};
  qk_gemm(eqHi, eqLo, etHi, etLo, gr0, gc0, t, SM, acc);

  const float sc = 0.08838834764831845f;   // 1/sqrt(128)
  #pragma unroll
  for(int m=0;m<4;m++){
    #pragma unroll
    for(int reg=0;reg<4;reg++){
      int l = wr*64 + m*16 + kg0*4 + reg;
      unsigned w0 = MB[l*4 + wc*2];
      unsigned w1 = MB[l*4 + wc*2 + 1];
      float s = 0.f;
      float p;
      p = ((w0 >> fr)      & 1u) ? __expf(acc[m][0][reg]*sc) : 0.f; s += p;
      p = ((w0 >> (fr+16)) & 1u) ? __expf(acc[m][1][reg]*sc) : 0.f; s += p;
      p = ((w1 >> fr)      & 1u) ? __expf(acc[m][2][reg]*sc) : 0.f; s += p;
      p = ((w1 >> (fr+16)) & 1u) ? __expf(acc[m][3][reg]*sc) : 0.f; s += p;
      s += __shfl_xor(s, 1);
      s += __shfl_xor(s, 2);
      s += __shfl_xor(s, 4);
      s += __shfl_xor(s, 8);
      if(fr == 0) atomicAdd(&rowsum[gr0 + l], s);
    }
  }
}

// ---------------- attention pass B: recompute, normalize, coalesced store ----------------
__global__ __launch_bounds__(256,2) void attout_k(
    const ushort* __restrict__ eqHi, const ushort* __restrict__ eqLo,
    const ushort* __restrict__ etHi, const ushort* __restrict__ etLo,
    const void* __restrict__ maskp, const int* __restrict__ flag,
    const unsigned* __restrict__ bitsIn, const float* __restrict__ rowsum,
    float* __restrict__ out){
  __shared__ float PT[128*132];            // 67.6 KB; low 64 KB aliased as staging
  __shared__ __align__(16) unsigned MB[512];
  __shared__ float IRS[128];
  ushort* SM = (ushort*)PT;
  int t = threadIdx.x;
  int gc0 = blockIdx.x * 128;
  int gr0 = blockIdx.y * 128;
  int lane = t & 63;
  int w = t >> 6;
  int wr = w >> 1, wc = w & 1;
  int fr = lane & 15, kg0 = lane >> 4;

  if(bitsIn){
    if(t < 128)
      *(uint4*)&MB[t*4] = *(const uint4*)&bitsIn[(size_t)(gr0 + t)*(N_T/32) + (gc0 >> 5)];
  } else {
    int mb = *flag;
    stage_mask_raw(maskp, mb, gr0, gc0, MB, t);
  }
  if(t < 128) IRS[t] = 1.0f / rowsum[gr0 + t];

  f32x4 acc[4][4] = {};
  qk_gemm(eqHi, eqLo, etHi, etLo, gr0, gc0, t, SM, acc);

  __syncthreads();   // all waves done reading SM before PT overwrite

  const float sc = 0.08838834764831845f;
  #pragma unroll
  for(int m=0;m<4;m++){
    #pragma unroll
    for(int reg=0;reg<4;reg++){
      int l = wr*64 + m*16 + kg0*4 + reg;
      unsigned w0 = MB[l*4 + wc*2];
      unsigned w1 = MB[l*4 + wc*2 + 1];
      float ir = IRS[l];
      int cb = wc*64 + fr;
      PT[l*132 + cb     ] = ((w0 >> fr)      & 1u) ? __expf(acc[m][0][reg]*sc)*ir : 0.f;
      PT[l*132 + cb + 16] = ((w0 >> (fr+16)) & 1u) ? __expf(acc[m][1][reg]*sc)*ir : 0.f;
      PT[l*132 + cb + 32] = ((w1 >> fr)      & 1u) ? __expf(acc[m][2][reg]*sc)*ir : 0.f;
      PT[l*132 + cb + 48] = ((w1 >> (fr+16)) & 1u) ? __expf(acc[m][3][reg]*sc)*ir : 0.f;
    }
  }
  __syncthreads();

  // coalesced float4 store of the 128x128 tile
  #pragma unroll
  for(int i=0;i<16;i++){
    int idx = t + i*256;               // 0..4095
    int row = idx >> 5, c4 = idx & 31;
    f32x4 v = *(const f32x4*)&PT[row*132 + c4*4];
    float4 o; o.x=v[0]; o.y=v[1]; o.z=v[2]; o.w=v[3];
    *(float4*)&out[(size_t)(gr0 + row)*N_T + gc0 + c4*4] = o;
  }
}

// ---------------- host launch ----------------
extern "C" void kernel_launch(void* const* d_in, const int* in_sizes, int n_in,
                              void* d_out, int out_size, void* d_ws, size_t ws_size,
                              hipStream_t stream){
  const int* tx  = (const int*)d_in[0];
  const int* qx  = (const int*)d_in[1];
  const int* te  = (const int*)d_in[2];
  const int* qe  = (const int*)d_in[3];
  const void* mask = d_in[4];
  const float* emb = (const float*)d_in[5];
  const float* Wl  = (const float*)d_in[6];
  const float* bl  = (const float*)d_in[7];
  const float* Wr  = (const float*)d_in[8];
  float* out = (float*)d_out;

  // ws layout: features bf16 hi/lo + rowsum + flag (+ bit-mask at 19MB)
  ushort* etHi = (ushort*)d_ws;                       // N_T*H
  ushort* etLo = etHi + (size_t)N_T*H;
  ushort* eqHi = etLo + (size_t)N_T*H;                // N_Q*H
  ushort* eqLo = eqHi + (size_t)N_Q*H;
  float* rowsum = (float*)(eqLo + (size_t)N_Q*H);
  int*   flag   = (int*)(rowsum + N_Q);
  bool useBits = ws_size >= ((size_t)37 << 20);
  unsigned* bits = useBits ? (unsigned*)((char*)d_ws + ((size_t)19 << 20)) : nullptr;

  // phase-1 scratch lives inside d_out (512MB; overwritten by attout afterwards)
  float* S    = out;
  float* xt0  = S;
  float* xt1  = S + 4194304;
  float* aggt = S + 8388608;
  float* xq0  = S + 12582912;
  float* xq1  = xq0 + 524288;
  float* aggq = xq1 + 524288;
  int*   ib    = (int*)(aggq + 524288);
  int*   cnt_t = ib;
  int*   rp_t  = cnt_t + N_T;
  int*   pos_t = rp_t + N_T + 1;
  int*   csr_t = pos_t + N_T;
  int*   cnt_q = csr_t + E_T;
  int*   rp_q  = cnt_q + N_Q;
  int*   pos_q = rp_q + N_Q + 1;
  int*   csr_q = pos_q + N_Q;

  zero_i32_k<<<(N_T+255)/256,256,0,stream>>>(cnt_t, N_T);
  zero_i32_k<<<(N_Q+255)/256,256,0,stream>>>(cnt_q, N_Q);
  zero_f32_k<<<(N_Q+255)/256,256,0,stream>>>(rowsum, N_Q);
  zero_i32_k<<<1,256,0,stream>>>(flag, 1);
  detect_mask_k<<<1,256,0,stream>>>((const unsigned*)mask, flag);
  if(bits) pack_mask_k<<<N_Q,256,0,stream>>>(mask, flag, bits);

  count_k<<<E_T/256,256,0,stream>>>(te+E_T, E_T, cnt_t);
  scan_k<<<1,1024,0,stream>>>(cnt_t, N_T, rp_t, pos_t);
  fill_k<<<E_T/256,256,0,stream>>>(te, te+E_T, E_T, pos_t, csr_t);
  count_k<<<E_Q/256,256,0,stream>>>(qe+E_Q, E_Q, cnt_q);
  scan_k<<<1,1024,0,stream>>>(cnt_q, N_Q, rp_q, pos_q);
  fill_k<<<E_Q/256,256,0,stream>>>(qe, qe+E_Q, E_Q, pos_q, csr_q);

  embed_k<<<N_T*32/256,256,0,stream>>>(tx, emb, xt0, N_T);
  embed_k<<<N_Q*32/256,256,0,stream>>>(qx, emb, xq0, N_Q);

  float* ct = xt0; float* nt = xt1;
  float* cq = xq0; float* nq = xq1;
  for(int l=0;l<NL;l++){
    int last = (l == NL-1);
    agg_k<<<N_T/4,256,0,stream>>>(ct, rp_t, csr_t, aggt, N_T);
    layer_k<<<N_T/128,256,0,stream>>>(aggt, ct, Wl+(size_t)l*H*H, Wr+(size_t)l*H*H,
                                      bl+(size_t)l*H, nt, etHi, etLo, N_T, last);
    agg_k<<<N_Q/4,256,0,stream>>>(cq, rp_q, csr_q, aggq, N_Q);
    layer_k<<<N_Q/128,256,0,stream>>>(aggq, cq, Wl+(size_t)l*H*H, Wr+(size_t)l*H*H,
                                      bl+(size_t)l*H, nq, eqHi, eqLo, N_Q, last);
    float* tmp;
    tmp = ct; ct = nt; nt = tmp;
    tmp = cq; cq = nq; nq = tmp;
  }

  attsum_k<<<dim3(N_T/128, N_Q/128),256,0,stream>>>(eqHi, eqLo, etHi, etLo,
                                                    mask, flag, bits, rowsum);
  attout_k<<<dim3(N_T/128, N_Q/128),256,0,stream>>>(eqHi, eqLo, etHi, etLo,
                                                    mask, flag, bits, rowsum, out);
}

// Round 5
// 1233.425 us; speedup vs baseline: 1.5539x; 1.1273x over previous
//
#include <hip/hip_runtime.h>
#include <stdint.h>

#define N_T 32768
#define N_Q 4096
#define E_T 1048576
#define E_Q 131072
#define H   128
#define NL  3

typedef float    f32x4 __attribute__((ext_vector_type(4)));
typedef _Float16 f16x8 __attribute__((ext_vector_type(8)));

// ---------------- utility kernels ----------------
__global__ void zero_i32_k(int* p, int n){
  int i = blockIdx.x*blockDim.x + threadIdx.x;
  if(i<n) p[i]=0;
}
__global__ void zero_f32_k(float* p, int n){
  int i = blockIdx.x*blockDim.x + threadIdx.x;
  if(i<n) p[i]=0.f;
}

// classify mask dtype: flag bit0 -> uint8 bools, bit1 -> float32, 0 -> int32
__global__ void detect_mask_k(const unsigned* m, int* flag){
  int t = threadIdx.x;
  int f = 0;
  for(int j=t;j<4096;j+=256){
    unsigned v = m[j];
    if(v > 1u) f |= (v & 0xFEFEFEFEu) ? 2 : 1;
  }
  if(f) atomicOr(flag, f);
}

// ---------------- mask -> packed bits (streaming, BW-bound) ----------------
__device__ __forceinline__ unsigned nib8(unsigned x, unsigned y){
  unsigned r = (x & 0xFu) | ((x>>4)&0xF0u) | ((x>>8)&0xF00u) | ((x>>12)&0xF000u);
  unsigned s = (y & 0xFu) | ((y>>4)&0xF0u) | ((y>>8)&0xF00u) | ((y>>12)&0xF000u);
  return r | (s<<16);
}

__global__ __launch_bounds__(256) void pack_mask_k(
    const void* __restrict__ maskp, const int* __restrict__ flag,
    unsigned* __restrict__ bits){
  __shared__ uint8_t NB[8192];
  int t = threadIdx.x;
  int r = blockIdx.x;
  int mb = *flag;
  size_t rbase = (size_t)r * N_T;
  if(mb & 2){
    const float* mp = (const float*)maskp + rbase;
    #pragma unroll 4
    for(int i=0;i<32;i++){
      float4 v = *(const float4*)&mp[i*1024 + t*4];
      unsigned nib = (v.x!=0.f) | ((v.y!=0.f)<<1) | ((v.z!=0.f)<<2) | ((v.w!=0.f)<<3);
      NB[i*256 + t] = (uint8_t)nib;
    }
  } else if(mb & 1){
    const uint8_t* mp = (const uint8_t*)maskp + rbase;
    #pragma unroll 4
    for(int i=0;i<32;i++){
      uchar4 v = *(const uchar4*)&mp[i*1024 + t*4];
      unsigned nib = (v.x!=0) | ((v.y!=0)<<1) | ((v.z!=0)<<2) | ((v.w!=0)<<3);
      NB[i*256 + t] = (uint8_t)nib;
    }
  } else {
    const int* mp = (const int*)maskp + rbase;
    #pragma unroll 4
    for(int i=0;i<32;i++){
      int4 v = *(const int4*)&mp[i*1024 + t*4];
      unsigned nib = (v.x!=0) | ((v.y!=0)<<1) | ((v.z!=0)<<2) | ((v.w!=0)<<3);
      NB[i*256 + t] = (uint8_t)nib;
    }
  }
  __syncthreads();
  uint4 a = *(const uint4*)&NB[32*t];
  uint4 b = *(const uint4*)&NB[32*t + 16];
  uint4 o;
  o.x = nib8(a.x, a.y);
  o.y = nib8(a.z, a.w);
  o.z = nib8(b.x, b.y);
  o.w = nib8(b.z, b.w);
  *(uint4*)&bits[(size_t)r*(N_T/32) + 4*t] = o;
}

// ---------------- CSR build ----------------
__global__ void count_k(const int* __restrict__ dst, int E, int* cnt){
  int i = blockIdx.x*blockDim.x + threadIdx.x;
  if(i<E) atomicAdd(&cnt[dst[i]], 1);
}

__global__ void scan_k(const int* __restrict__ cnt, int n, int* rp, int* pos){
  __shared__ int part[1024];
  int t = threadIdx.x;
  int chunk = (n + 1023) >> 10;
  int lo = t*chunk, hi = lo+chunk; if(hi>n) hi=n;
  int s = 0;
  for(int i=lo;i<hi;i++) s += cnt[i];
  part[t] = s;
  __syncthreads();
  for(int off=1; off<1024; off<<=1){
    int v = (t >= off) ? part[t-off] : 0;
    __syncthreads();
    part[t] += v;
    __syncthreads();
  }
  int run = (t==0) ? 0 : part[t-1];
  for(int i=lo;i<hi;i++){ rp[i]=run; pos[i]=run; run += cnt[i]; }
  if(t==0) rp[n] = part[1023];
}

__global__ void fill_k(const int* __restrict__ src, const int* __restrict__ dst,
                       int E, int* pos, int* csr){
  int i = blockIdx.x*blockDim.x + threadIdx.x;
  if(i<E){
    int p = atomicAdd(&pos[dst[i]], 1);
    csr[p] = src[i];
  }
}

// ---------------- embedding gather ----------------
__global__ void embed_k(const int* __restrict__ idx, const float* __restrict__ emb,
                        float* __restrict__ out, int N){
  int i = blockIdx.x*blockDim.x + threadIdx.x;
  int n = i >> 5, c = i & 31;
  if(n < N){
    ((float4*)out)[(size_t)n*32 + c] = ((const float4*)emb)[(size_t)idx[n]*32 + c];
  }
}

// ---------------- segment mean (one wave per dst node, 4 rows in flight) ----------------
__global__ void agg_k(const float* __restrict__ x, const int* __restrict__ rp,
                      const int* __restrict__ csr, float* __restrict__ agg, int N){
  int wid = (int)(((size_t)blockIdx.x*blockDim.x + threadIdx.x) >> 6);
  int lane = threadIdx.x & 63;
  if(wid >= N) return;
  int rs = rp[wid], re = rp[wid+1];
  float ax=0.f, ay=0.f, bx=0.f, by=0.f, cx=0.f, cy=0.f, dx=0.f, dy=0.f;
  int j = rs;
  for(; j+4 <= re; j+=4){
    int s0 = csr[j], s1 = csr[j+1], s2 = csr[j+2], s3 = csr[j+3];
    float2 v0 = ((const float2*)x)[(size_t)s0*64 + lane];
    float2 v1 = ((const float2*)x)[(size_t)s1*64 + lane];
    float2 v2 = ((const float2*)x)[(size_t)s2*64 + lane];
    float2 v3 = ((const float2*)x)[(size_t)s3*64 + lane];
    ax += v0.x; ay += v0.y;
    bx += v1.x; by += v1.y;
    cx += v2.x; cy += v2.y;
    dx += v3.x; dy += v3.y;
  }
  for(; j < re; j++){
    int s = csr[j];
    float2 v = ((const float2*)x)[(size_t)s*64 + lane];
    ax += v.x; ay += v.y;
  }
  float sx = (ax + bx) + (cx + dx);
  float sy = (ay + by) + (cy + dy);
  int c = re - rs; if(c < 1) c = 1;
  float inv = 1.0f / (float)c;
  float2 o; o.x = sx*inv; o.y = sy*inv;
  ((float2*)agg)[(size_t)wid*64 + lane] = o;
}

// ---------------- layer GEMM: out = elu(agg@Wl.T + bl + x@Wr.T) ----------------
__global__ __launch_bounds__(256,1) void layer_k(
    const float* __restrict__ agg, const float* __restrict__ x,
    const float* __restrict__ Wl, const float* __restrict__ Wr,
    const float* __restrict__ bl, float* __restrict__ outf,
    ushort* __restrict__ out16,
    int N, int last){
  __shared__ float WT[128*128];
  __shared__ float AT[128*128];
  int t = threadIdx.x;
  int r0g = blockIdx.x * 128;
  int rg = t & 15, cg = t >> 4;
  int r0 = rg*8, c0 = cg*8;
  float acc[8][8] = {};
  for(int ph=0; ph<2; ph++){
    const float* W = ph ? Wr : Wl;
    const float* A = ph ? x : agg;
    if(ph) __syncthreads();
    #pragma unroll
    for(int i=0;i<16;i++){
      int lin = t + i*256;
      int c = lin & 127, kg = lin >> 7;
      float4 w = *(const float4*)&W[(size_t)c*H + kg*4];
      WT[(kg*4+0)*128 + c] = w.x;
      WT[(kg*4+1)*128 + c] = w.y;
      WT[(kg*4+2)*128 + c] = w.z;
      WT[(kg*4+3)*128 + c] = w.w;
      float4 a = *(const float4*)&A[(size_t)(r0g + c)*H + kg*4];
      AT[(kg*4+0)*128 + c] = a.x;
      AT[(kg*4+1)*128 + c] = a.y;
      AT[(kg*4+2)*128 + c] = a.z;
      AT[(kg*4+3)*128 + c] = a.w;
    }
    __syncthreads();
    for(int k=0;k<128;k++){
      float4 a0 = *(float4*)&AT[k*128 + r0];
      float4 a1 = *(float4*)&AT[k*128 + r0+4];
      float4 w0 = *(float4*)&WT[k*128 + c0];
      float4 w1 = *(float4*)&WT[k*128 + c0+4];
      float av[8] = {a0.x,a0.y,a0.z,a0.w,a1.x,a1.y,a1.z,a1.w};
      float wv[8] = {w0.x,w0.y,w0.z,w0.w,w1.x,w1.y,w1.z,w1.w};
      #pragma unroll
      for(int rr=0;rr<8;rr++)
        #pragma unroll
        for(int cc=0;cc<8;cc++)
          acc[rr][cc] += av[rr]*wv[cc];
    }
  }
  #pragma unroll
  for(int rr=0;rr<8;rr++)
    #pragma unroll
    for(int cc=0;cc<8;cc++){
      float v = acc[rr][cc] + bl[c0+cc];
      acc[rr][cc] = (v > 0.f) ? v : expm1f(v);
    }
  if(!last){
    #pragma unroll
    for(int rr=0;rr<8;rr++){
      float4 v0; v0.x=acc[rr][0]; v0.y=acc[rr][1]; v0.z=acc[rr][2]; v0.w=acc[rr][3];
      float4 v1; v1.x=acc[rr][4]; v1.y=acc[rr][5]; v1.z=acc[rr][6]; v1.w=acc[rr][7];
      size_t off = (size_t)(r0g + r0 + rr)*H + c0;
      *(float4*)&outf[off]   = v0;
      *(float4*)&outf[off+4] = v1;
    }
  } else {
    #pragma unroll
    for(int rr=0;rr<8;rr++){
      ushort hh[8];
      #pragma unroll
      for(int cc=0;cc<8;cc++){
        union { _Float16 h; ushort u; } cv;
        cv.h = (_Float16)acc[rr][cc];
        hh[cc] = cv.u;
      }
      uint4 hv;
      hv.x = (unsigned)hh[0] | ((unsigned)hh[1]<<16);
      hv.y = (unsigned)hh[2] | ((unsigned)hh[3]<<16);
      hv.z = (unsigned)hh[4] | ((unsigned)hh[5]<<16);
      hv.w = (unsigned)hh[6] | ((unsigned)hh[7]<<16);
      size_t off = (size_t)(r0g + r0 + rr)*H + c0;
      *(uint4*)&out16[off] = hv;
    }
  }
}

// ---------------- attention helpers ----------------
// fallback: stage 128x128 mask tile as packed bits into MB[512]
__device__ __forceinline__ void stage_mask_raw(const void* maskp, int mb,
                                               int gr0, int gc0, unsigned* MB, int t){
  int wv = t >> 6, lane = t & 63;
  #pragma unroll 8
  for(int i=0;i<64;i++){
    int id = i*4 + wv;
    int r = id >> 1, c64 = id & 1;
    size_t off = (size_t)(gr0 + r)*N_T + gc0 + c64*64 + lane;
    bool pred;
    if(mb & 2)      pred = (((const float*)maskp)[off]   != 0.f);
    else if(mb & 1) pred = (((const uint8_t*)maskp)[off] != 0);
    else            pred = (((const int*)maskp)[off]     != 0);
    unsigned long long b = __ballot(pred);
    if(lane == 0){
      MB[r*4 + c64*2]     = (unsigned)b;
      MB[r*4 + c64*2 + 1] = (unsigned)(b >> 32);
    }
  }
}

// fp16 QK^T GEMM core: 128x128 tile, 4 waves (2x2), 64x64/wave, K in two 64-halves
__device__ __forceinline__ void qk_gemm(
    const ushort* __restrict__ eq16, const ushort* __restrict__ et16,
    int gr0, int gc0, int t, ushort* SM, f32x4 (&acc)[4][4]){
  ushort* Q = SM;            // [128][64] swizzled
  ushort* T = SM + 8192;
  int lane = t & 63;
  int w = t >> 6;
  int wr = w >> 1, wc = w & 1;
  int fr = lane & 15, kg0 = lane >> 4;
  for(int kt=0; kt<2; kt++){
    __syncthreads();
    #pragma unroll
    for(int it=0; it<4; it++){
      int idx = t + it*256;          // 0..1023
      int row = idx >> 3, k8 = idx & 7;
      int sw = (k8 ^ (row & 7)) * 8;
      *(uint4*)&Q[row*64 + sw] = *(const uint4*)&eq16[(size_t)(gr0+row)*H + kt*64 + k8*8];
      *(uint4*)&T[row*64 + sw] = *(const uint4*)&et16[(size_t)(gc0+row)*H + kt*64 + k8*8];
    }
    __syncthreads();
    #pragma unroll
    for(int s=0; s<2; s++){
      int kg = s*4 + kg0;
      f16x8 a[4], b[4];
      #pragma unroll
      for(int m=0;m<4;m++){
        int ar = wr*64 + m*16 + fr;
        a[m] = *(const f16x8*)&Q[ar*64 + ((kg ^ (ar & 7)) << 3)];
      }
      #pragma unroll
      for(int n=0;n<4;n++){
        int bc = wc*64 + n*16 + fr;
        b[n] = *(const f16x8*)&T[bc*64 + ((kg ^ (bc & 7)) << 3)];
      }
      #pragma unroll
      for(int m=0;m<4;m++)
        #pragma unroll
        for(int n=0;n<4;n++)
          acc[m][n] = __builtin_amdgcn_mfma_f32_16x16x32_f16(a[m], b[n], acc[m][n], 0,0,0);
    }
  }
}

// ---------------- attention pass A: rowsums ----------------
__global__ __launch_bounds__(256,4) void attsum_k(
    const ushort* __restrict__ eq16, const ushort* __restrict__ et16,
    const void* __restrict__ maskp, const int* __restrict__ flag,
    const unsigned* __restrict__ bitsIn, float* __restrict__ rowsum){
  __shared__ ushort SM[2*128*64];       // 32 KB
  __shared__ __align__(16) unsigned MB[512];
  int t = threadIdx.x;
  int gc0 = blockIdx.x * 128;
  int gr0 = blockIdx.y * 128;
  int lane = t & 63;
  int w = t >> 6;
  int wr = w >> 1, wc = w & 1;
  int fr = lane & 15, kg0 = lane >> 4;

  if(bitsIn){
    if(t < 128)
      *(uint4*)&MB[t*4] = *(const uint4*)&bitsIn[(size_t)(gr0 + t)*(N_T/32) + (gc0 >> 5)];
  } else {
    int mb = *flag;
    stage_mask_raw(maskp, mb, gr0, gc0, MB, t);
  }

  f32x4 acc[4][4] = {};
  qk_gemm(eq16, et16, gr0, gc0, t, SM, acc);

  const float sc = 0.08838834764831845f;   // 1/sqrt(128)
  #pragma unroll
  for(int m=0;m<4;m++){
    #pragma unroll
    for(int reg=0;reg<4;reg++){
      int l = wr*64 + m*16 + kg0*4 + reg;
      unsigned w0 = MB[l*4 + wc*2];
      unsigned w1 = MB[l*4 + wc*2 + 1];
      float s = 0.f;
      float p;
      p = ((w0 >> fr)      & 1u) ? __expf(acc[m][0][reg]*sc) : 0.f; s += p;
      p = ((w0 >> (fr+16)) & 1u) ? __expf(acc[m][1][reg]*sc) : 0.f; s += p;
      p = ((w1 >> fr)      & 1u) ? __expf(acc[m][2][reg]*sc) : 0.f; s += p;
      p = ((w1 >> (fr+16)) & 1u) ? __expf(acc[m][3][reg]*sc) : 0.f; s += p;
      s += __shfl_xor(s, 1);
      s += __shfl_xor(s, 2);
      s += __shfl_xor(s, 4);
      s += __shfl_xor(s, 8);
      if(fr == 0) atomicAdd(&rowsum[gr0 + l], s);
    }
  }
}

// ---------------- attention pass B: recompute, normalize, coalesced store ----------------
__global__ __launch_bounds__(256,2) void attout_k(
    const ushort* __restrict__ eq16, const ushort* __restrict__ et16,
    const void* __restrict__ maskp, const int* __restrict__ flag,
    const unsigned* __restrict__ bitsIn, const float* __restrict__ rowsum,
    float* __restrict__ out){
  __shared__ float PT[128*132];            // 67.6 KB; low 32 KB aliased as staging
  __shared__ __align__(16) unsigned MB[512];
  __shared__ float IRS[128];
  ushort* SM = (ushort*)PT;
  int t = threadIdx.x;
  int gc0 = blockIdx.x * 128;
  int gr0 = blockIdx.y * 128;
  int lane = t & 63;
  int w = t >> 6;
  int wr = w >> 1, wc = w & 1;
  int fr = lane & 15, kg0 = lane >> 4;

  if(bitsIn){
    if(t < 128)
      *(uint4*)&MB[t*4] = *(const uint4*)&bitsIn[(size_t)(gr0 + t)*(N_T/32) + (gc0 >> 5)];
  } else {
    int mb = *flag;
    stage_mask_raw(maskp, mb, gr0, gc0, MB, t);
  }
  if(t < 128) IRS[t] = 1.0f / rowsum[gr0 + t];

  f32x4 acc[4][4] = {};
  qk_gemm(eq16, et16, gr0, gc0, t, SM, acc);

  __syncthreads();   // all waves done reading SM before PT overwrite

  const float sc = 0.08838834764831845f;
  #pragma unroll
  for(int m=0;m<4;m++){
    #pragma unroll
    for(int reg=0;reg<4;reg++){
      int l = wr*64 + m*16 + kg0*4 + reg;
      unsigned w0 = MB[l*4 + wc*2];
      unsigned w1 = MB[l*4 + wc*2 + 1];
      float ir = IRS[l];
      int cb = wc*64 + fr;
      PT[l*132 + cb     ] = ((w0 >> fr)      & 1u) ? __expf(acc[m][0][reg]*sc)*ir : 0.f;
      PT[l*132 + cb + 16] = ((w0 >> (fr+16)) & 1u) ? __expf(acc[m][1][reg]*sc)*ir : 0.f;
      PT[l*132 + cb + 32] = ((w1 >> fr)      & 1u) ? __expf(acc[m][2][reg]*sc)*ir : 0.f;
      PT[l*132 + cb + 48] = ((w1 >> (fr+16)) & 1u) ? __expf(acc[m][3][reg]*sc)*ir : 0.f;
    }
  }
  __syncthreads();

  // coalesced float4 store of the 128x128 tile
  #pragma unroll
  for(int i=0;i<16;i++){
    int idx = t + i*256;
    int row = idx >> 5, c4 = idx & 31;
    f32x4 v = *(const f32x4*)&PT[row*132 + c4*4];
    float4 o; o.x=v[0]; o.y=v[1]; o.z=v[2]; o.w=v[3];
    *(float4*)&out[(size_t)(gr0 + row)*N_T + gc0 + c4*4] = o;
  }
}

// ---------------- host launch ----------------
extern "C" void kernel_launch(void* const* d_in, const int* in_sizes, int n_in,
                              void* d_out, int out_size, void* d_ws, size_t ws_size,
                              hipStream_t stream){
  const int* tx  = (const int*)d_in[0];
  const int* qx  = (const int*)d_in[1];
  const int* te  = (const int*)d_in[2];
  const int* qe  = (const int*)d_in[3];
  const void* mask = d_in[4];
  const float* emb = (const float*)d_in[5];
  const float* Wl  = (const float*)d_in[6];
  const float* bl  = (const float*)d_in[7];
  const float* Wr  = (const float*)d_in[8];
  float* out = (float*)d_out;

  // ws layout: fp16 features + rowsum + flag (+ bit-mask at 19MB)
  ushort* et16 = (ushort*)d_ws;                       // N_T*H (8 MB)
  ushort* eq16 = et16 + (size_t)N_T*H;                // N_Q*H (1 MB)
  float* rowsum = (float*)(eq16 + (size_t)N_Q*H);
  int*   flag   = (int*)(rowsum + N_Q);
  bool useBits = ws_size >= ((size_t)37 << 20);
  unsigned* bits = useBits ? (unsigned*)((char*)d_ws + ((size_t)19 << 20)) : nullptr;

  // phase-1 scratch lives inside d_out (512MB; overwritten by attout afterwards)
  float* S    = out;
  float* xt0  = S;
  float* xt1  = S + 4194304;
  float* aggt = S + 8388608;
  float* xq0  = S + 12582912;
  float* xq1  = xq0 + 524288;
  float* aggq = xq1 + 524288;
  int*   ib    = (int*)(aggq + 524288);
  int*   cnt_t = ib;
  int*   rp_t  = cnt_t + N_T;
  int*   pos_t = rp_t + N_T + 1;
  int*   csr_t = pos_t + N_T;
  int*   cnt_q = csr_t + E_T;
  int*   rp_q  = cnt_q + N_Q;
  int*   pos_q = rp_q + N_Q + 1;
  int*   csr_q = pos_q + N_Q;

  zero_i32_k<<<(N_T+255)/256,256,0,stream>>>(cnt_t, N_T);
  zero_i32_k<<<(N_Q+255)/256,256,0,stream>>>(cnt_q, N_Q);
  zero_f32_k<<<(N_Q+255)/256,256,0,stream>>>(rowsum, N_Q);
  zero_i32_k<<<1,256,0,stream>>>(flag, 1);
  detect_mask_k<<<1,256,0,stream>>>((const unsigned*)mask, flag);
  if(bits) pack_mask_k<<<N_Q,256,0,stream>>>(mask, flag, bits);

  count_k<<<E_T/256,256,0,stream>>>(te+E_T, E_T, cnt_t);
  scan_k<<<1,1024,0,stream>>>(cnt_t, N_T, rp_t, pos_t);
  fill_k<<<E_T/256,256,0,stream>>>(te, te+E_T, E_T, pos_t, csr_t);
  count_k<<<E_Q/256,256,0,stream>>>(qe+E_Q, E_Q, cnt_q);
  scan_k<<<1,1024,0,stream>>>(cnt_q, N_Q, rp_q, pos_q);
  fill_k<<<E_Q/256,256,0,stream>>>(qe, qe+E_Q, E_Q, pos_q, csr_q);

  embed_k<<<N_T*32/256,256,0,stream>>>(tx, emb, xt0, N_T);
  embed_k<<<N_Q*32/256,256,0,stream>>>(qx, emb, xq0, N_Q);

  float* ct = xt0; float* nt = xt1;
  float* cq = xq0; float* nq = xq1;
  for(int l=0;l<NL;l++){
    int last = (l == NL-1);
    agg_k<<<N_T/4,256,0,stream>>>(ct, rp_t, csr_t, aggt, N_T);
    layer_k<<<N_T/128,256,0,stream>>>(aggt, ct, Wl+(size_t)l*H*H, Wr+(size_t)l*H*H,
                                      bl+(size_t)l*H, nt, et16, N_T, last);
    agg_k<<<N_Q/4,256,0,stream>>>(cq, rp_q, csr_q, aggq, N_Q);
    layer_k<<<N_Q/128,256,0,stream>>>(aggq, cq, Wl+(size_t)l*H*H, Wr+(size_t)l*H*H,
                                      bl+(size_t)l*H, nq, eq16, N_Q, last);
    float* tmp;
    tmp = ct; ct = nt; nt = tmp;
    tmp = cq; cq = nq; nq = tmp;
  }

  attsum_k<<<dim3(N_T/128, N_Q/128),256,0,stream>>>(eq16, et16, mask, flag, bits, rowsum);
  attout_k<<<dim3(N_T/128, N_Q/128),256,0,stream>>>(eq16, et16, mask, flag, bits, rowsum, out);
}

// Round 6
// 1000.377 us; speedup vs baseline: 1.9160x; 1.2330x over previous
//
#include <hip/hip_runtime.h>
#include <stdint.h>

#define N_T 32768
#define N_Q 4096
#define E_T 1048576
#define E_Q 131072
#define H   128
#define NL  3

typedef float    f32x4 __attribute__((ext_vector_type(4)));
typedef _Float16 f16x8 __attribute__((ext_vector_type(8)));

__device__ __forceinline__ ushort f2h(float x){
  union{_Float16 h; ushort u;} c; c.h = (_Float16)x; return c.u;
}
__device__ __forceinline__ float h2f(unsigned u){
  union{ushort u; _Float16 h;} c; c.u = (ushort)u; return (float)c.h;
}

// ---------------- utility kernels ----------------
__global__ void zero_i32_k(int* p, int n){
  int i = blockIdx.x*blockDim.x + threadIdx.x;
  if(i<n) p[i]=0;
}
__global__ void zero_f32_k(float* p, int n){
  int i = blockIdx.x*blockDim.x + threadIdx.x;
  if(i<n) p[i]=0.f;
}

// classify mask dtype: flag bit0 -> uint8 bools, bit1 -> float32, 0 -> int32
__global__ void detect_mask_k(const unsigned* m, int* flag){
  int t = threadIdx.x;
  int f = 0;
  for(int j=t;j<4096;j+=256){
    unsigned v = m[j];
    if(v > 1u) f |= (v & 0xFEFEFEFEu) ? 2 : 1;
  }
  if(f) atomicOr(flag, f);
}

// ---------------- mask -> packed bits (streaming, BW-bound) ----------------
__device__ __forceinline__ unsigned nib8(unsigned x, unsigned y){
  unsigned r = (x & 0xFu) | ((x>>4)&0xF0u) | ((x>>8)&0xF00u) | ((x>>12)&0xF000u);
  unsigned s = (y & 0xFu) | ((y>>4)&0xF0u) | ((y>>8)&0xF00u) | ((y>>12)&0xF000u);
  return r | (s<<16);
}

__global__ __launch_bounds__(256) void pack_mask_k(
    const void* __restrict__ maskp, const int* __restrict__ flag,
    unsigned* __restrict__ bits){
  __shared__ uint8_t NB[8192];
  int t = threadIdx.x;
  int r = blockIdx.x;
  int mb = *flag;
  size_t rbase = (size_t)r * N_T;
  if(mb & 2){
    const float* mp = (const float*)maskp + rbase;
    #pragma unroll 4
    for(int i=0;i<32;i++){
      float4 v = *(const float4*)&mp[i*1024 + t*4];
      unsigned nib = (v.x!=0.f) | ((v.y!=0.f)<<1) | ((v.z!=0.f)<<2) | ((v.w!=0.f)<<3);
      NB[i*256 + t] = (uint8_t)nib;
    }
  } else if(mb & 1){
    const uint8_t* mp = (const uint8_t*)maskp + rbase;
    #pragma unroll 4
    for(int i=0;i<32;i++){
      uchar4 v = *(const uchar4*)&mp[i*1024 + t*4];
      unsigned nib = (v.x!=0) | ((v.y!=0)<<1) | ((v.z!=0)<<2) | ((v.w!=0)<<3);
      NB[i*256 + t] = (uint8_t)nib;
    }
  } else {
    const int* mp = (const int*)maskp + rbase;
    #pragma unroll 4
    for(int i=0;i<32;i++){
      int4 v = *(const int4*)&mp[i*1024 + t*4];
      unsigned nib = (v.x!=0) | ((v.y!=0)<<1) | ((v.z!=0)<<2) | ((v.w!=0)<<3);
      NB[i*256 + t] = (uint8_t)nib;
    }
  }
  __syncthreads();
  uint4 a = *(const uint4*)&NB[32*t];
  uint4 b = *(const uint4*)&NB[32*t + 16];
  uint4 o;
  o.x = nib8(a.x, a.y);
  o.y = nib8(a.z, a.w);
  o.z = nib8(b.x, b.y);
  o.w = nib8(b.z, b.w);
  *(uint4*)&bits[(size_t)r*(N_T/32) + 4*t] = o;
}

// ---------------- CSR build ----------------
__global__ void count_k(const int* __restrict__ dst, int E, int* cnt){
  int i = blockIdx.x*blockDim.x + threadIdx.x;
  if(i<E) atomicAdd(&cnt[dst[i]], 1);
}

__global__ void scan_k(const int* __restrict__ cnt, int n, int* rp, int* pos){
  __shared__ int part[1024];
  int t = threadIdx.x;
  int chunk = (n + 1023) >> 10;
  int lo = t*chunk, hi = lo+chunk; if(hi>n) hi=n;
  int s = 0;
  for(int i=lo;i<hi;i++) s += cnt[i];
  part[t] = s;
  __syncthreads();
  for(int off=1; off<1024; off<<=1){
    int v = (t >= off) ? part[t-off] : 0;
    __syncthreads();
    part[t] += v;
    __syncthreads();
  }
  int run = (t==0) ? 0 : part[t-1];
  for(int i=lo;i<hi;i++){ rp[i]=run; pos[i]=run; run += cnt[i]; }
  if(t==0) rp[n] = part[1023];
}

__global__ void fill_k(const int* __restrict__ src, const int* __restrict__ dst,
                       int E, int* pos, int* csr){
  int i = blockIdx.x*blockDim.x + threadIdx.x;
  if(i<E){
    int p = atomicAdd(&pos[dst[i]], 1);
    csr[p] = src[i];
  }
}

// ---------------- embedding gather (f32 table -> fp16 features) ----------------
__global__ void embed_k(const int* __restrict__ idx, const float* __restrict__ emb,
                        ushort* __restrict__ out, int N){
  int i = blockIdx.x*blockDim.x + threadIdx.x;   // N*16 threads
  int n = i >> 4, c = i & 15;
  if(n < N){
    size_t eb = (size_t)idx[n]*32 + c*2;
    float4 v0 = ((const float4*)emb)[eb];
    float4 v1 = ((const float4*)emb)[eb+1];
    uint4 o;
    o.x = (unsigned)f2h(v0.x) | ((unsigned)f2h(v0.y)<<16);
    o.y = (unsigned)f2h(v0.z) | ((unsigned)f2h(v0.w)<<16);
    o.z = (unsigned)f2h(v1.x) | ((unsigned)f2h(v1.y)<<16);
    o.w = (unsigned)f2h(v1.z) | ((unsigned)f2h(v1.w)<<16);
    ((uint4*)out)[(size_t)n*16 + c] = o;
  }
}

// ---------------- segment mean (fp16 features, one wave per dst node) ----------------
__global__ void agg_k(const ushort* __restrict__ x, const int* __restrict__ rp,
                      const int* __restrict__ csr, ushort* __restrict__ agg, int N){
  int wid = (int)(((size_t)blockIdx.x*blockDim.x + threadIdx.x) >> 6);
  int lane = threadIdx.x & 63;
  if(wid >= N) return;
  const unsigned* xp = (const unsigned*)x;     // 2 fp16 per word
  int rs = rp[wid], re = rp[wid+1];
  float ax=0.f, ay=0.f, bx=0.f, by=0.f, cx=0.f, cy=0.f, dx=0.f, dy=0.f;
  int j = rs;
  for(; j+4 <= re; j+=4){
    int s0 = csr[j], s1 = csr[j+1], s2 = csr[j+2], s3 = csr[j+3];
    unsigned u0 = xp[(size_t)s0*64 + lane];
    unsigned u1 = xp[(size_t)s1*64 + lane];
    unsigned u2 = xp[(size_t)s2*64 + lane];
    unsigned u3 = xp[(size_t)s3*64 + lane];
    ax += h2f(u0 & 0xFFFFu); ay += h2f(u0 >> 16);
    bx += h2f(u1 & 0xFFFFu); by += h2f(u1 >> 16);
    cx += h2f(u2 & 0xFFFFu); cy += h2f(u2 >> 16);
    dx += h2f(u3 & 0xFFFFu); dy += h2f(u3 >> 16);
  }
  for(; j < re; j++){
    unsigned u = xp[(size_t)csr[j]*64 + lane];
    ax += h2f(u & 0xFFFFu); ay += h2f(u >> 16);
  }
  float sx = (ax + bx) + (cx + dx);
  float sy = (ay + by) + (cy + dy);
  int c = re - rs; if(c < 1) c = 1;
  float inv = 1.0f / (float)c;
  ((unsigned*)agg)[(size_t)wid*64 + lane] =
      (unsigned)f2h(sx*inv) | ((unsigned)f2h(sy*inv) << 16);
}

// ---------------- layer GEMM: out = elu(agg@Wl.T + bl + x@Wr.T), fp16 in/out ----------------
__global__ __launch_bounds__(256,1) void layer_k(
    const ushort* __restrict__ agg, const ushort* __restrict__ x,
    const float* __restrict__ Wl, const float* __restrict__ Wr,
    const float* __restrict__ bl, ushort* __restrict__ out16, int N){
  __shared__ float WT[128*128];
  __shared__ float AT[128*128];
  int t = threadIdx.x;
  int r0g = blockIdx.x * 128;
  int rg = t & 15, cg = t >> 4;
  int r0 = rg*8, c0 = cg*8;
  float acc[8][8] = {};
  for(int ph=0; ph<2; ph++){
    const float* W = ph ? Wr : Wl;
    const ushort* A = ph ? x : agg;
    if(ph) __syncthreads();
    #pragma unroll
    for(int i=0;i<16;i++){
      int lin = t + i*256;
      int c = lin & 127, kg = lin >> 7;
      float4 w = *(const float4*)&W[(size_t)c*H + kg*4];
      WT[(kg*4+0)*128 + c] = w.x;
      WT[(kg*4+1)*128 + c] = w.y;
      WT[(kg*4+2)*128 + c] = w.z;
      WT[(kg*4+3)*128 + c] = w.w;
      ushort4 a4 = *(const ushort4*)&A[(size_t)(r0g + c)*H + kg*4];
      AT[(kg*4+0)*128 + c] = h2f(a4.x);
      AT[(kg*4+1)*128 + c] = h2f(a4.y);
      AT[(kg*4+2)*128 + c] = h2f(a4.z);
      AT[(kg*4+3)*128 + c] = h2f(a4.w);
    }
    __syncthreads();
    for(int k=0;k<128;k++){
      float4 a0 = *(float4*)&AT[k*128 + r0];
      float4 a1 = *(float4*)&AT[k*128 + r0+4];
      float4 w0 = *(float4*)&WT[k*128 + c0];
      float4 w1 = *(float4*)&WT[k*128 + c0+4];
      float av[8] = {a0.x,a0.y,a0.z,a0.w,a1.x,a1.y,a1.z,a1.w};
      float wv[8] = {w0.x,w0.y,w0.z,w0.w,w1.x,w1.y,w1.z,w1.w};
      #pragma unroll
      for(int rr=0;rr<8;rr++)
        #pragma unroll
        for(int cc=0;cc<8;cc++)
          acc[rr][cc] += av[rr]*wv[cc];
    }
  }
  #pragma unroll
  for(int rr=0;rr<8;rr++){
    ushort hh[8];
    #pragma unroll
    for(int cc=0;cc<8;cc++){
      float v = acc[rr][cc] + bl[c0+cc];
      v = (v > 0.f) ? v : expm1f(v);
      hh[cc] = f2h(v);
    }
    uint4 hv;
    hv.x = (unsigned)hh[0] | ((unsigned)hh[1]<<16);
    hv.y = (unsigned)hh[2] | ((unsigned)hh[3]<<16);
    hv.z = (unsigned)hh[4] | ((unsigned)hh[5]<<16);
    hv.w = (unsigned)hh[6] | ((unsigned)hh[7]<<16);
    size_t off = (size_t)(r0g + r0 + rr)*H + c0;
    *(uint4*)&out16[off] = hv;
  }
}

// ---------------- attention helpers ----------------
// fallback: stage 128x128 mask tile as packed bits into MB[512] (q rows, t cols)
__device__ __forceinline__ void stage_mask_raw(const void* maskp, int mb,
                                               int gr0, int gc0, unsigned* MB, int t){
  int wv = t >> 6, lane = t & 63;
  #pragma unroll 8
  for(int i=0;i<64;i++){
    int id = i*4 + wv;
    int r = id >> 1, c64 = id & 1;
    size_t off = (size_t)(gr0 + r)*N_T + gc0 + c64*64 + lane;
    bool pred;
    if(mb & 2)      pred = (((const float*)maskp)[off]   != 0.f);
    else if(mb & 1) pred = (((const uint8_t*)maskp)[off] != 0);
    else            pred = (((const int*)maskp)[off]     != 0);
    unsigned long long b = __ballot(pred);
    if(lane == 0){
      MB[r*4 + c64*2]     = (unsigned)b;
      MB[r*4 + c64*2 + 1] = (unsigned)(b >> 32);
    }
  }
}

// fp16 S^T GEMM core: A = et (M=target), B = eq (N=query). 128x128 tile, 4 waves.
// acc[m][n]: t_local = wr*64 + m*16 + (lane>>4)*4 + reg, q_local = wc*64 + n*16 + (lane&15)
__device__ __forceinline__ void qk_gemm(
    const ushort* __restrict__ A16, const ushort* __restrict__ B16,
    int abase, int bbase, int t, ushort* SM, f32x4 (&acc)[4][4]){
  ushort* AB = SM;            // [128][64] swizzled, et rows
  ushort* BB = SM + 8192;     // eq rows
  int lane = t & 63;
  int w = t >> 6;
  int wr = w >> 1, wc = w & 1;
  int fr = lane & 15, kg0 = lane >> 4;
  for(int kt=0; kt<2; kt++){
    __syncthreads();
    #pragma unroll
    for(int it=0; it<4; it++){
      int idx = t + it*256;          // 0..1023
      int row = idx >> 3, k8 = idx & 7;
      int sw = (k8 ^ (row & 7)) * 8;
      *(uint4*)&AB[row*64 + sw] = *(const uint4*)&A16[(size_t)(abase+row)*H + kt*64 + k8*8];
      *(uint4*)&BB[row*64 + sw] = *(const uint4*)&B16[(size_t)(bbase+row)*H + kt*64 + k8*8];
    }
    __syncthreads();
    #pragma unroll
    for(int s=0; s<2; s++){
      int kg = s*4 + kg0;
      f16x8 a[4], b[4];
      #pragma unroll
      for(int m=0;m<4;m++){
        int ar = wr*64 + m*16 + fr;
        a[m] = *(const f16x8*)&AB[ar*64 + ((kg ^ (ar & 7)) << 3)];
      }
      #pragma unroll
      for(int n=0;n<4;n++){
        int bc = wc*64 + n*16 + fr;
        b[n] = *(const f16x8*)&BB[bc*64 + ((kg ^ (bc & 7)) << 3)];
      }
      #pragma unroll
      for(int m=0;m<4;m++)
        #pragma unroll
        for(int n=0;n<4;n++)
          acc[m][n] = __builtin_amdgcn_mfma_f32_16x16x32_f16(a[m], b[n], acc[m][n], 0,0,0);
    }
  }
}

// ---------------- attention pass A: rowsums ----------------
__global__ __launch_bounds__(256,4) void attsum_k(
    const ushort* __restrict__ eq16, const ushort* __restrict__ et16,
    const void* __restrict__ maskp, const int* __restrict__ flag,
    const unsigned* __restrict__ bitsIn, float* __restrict__ rowsum){
  __shared__ ushort SM[2*128*64];       // 32 KB
  __shared__ __align__(16) unsigned MB[512];
  __shared__ float RS[128][2];
  int t = threadIdx.x;
  int gc0 = blockIdx.x * 128;   // target base
  int gr0 = blockIdx.y * 128;   // query base
  int lane = t & 63;
  int w = t >> 6;
  int wr = w >> 1, wc = w & 1;
  int fr = lane & 15, kg0 = lane >> 4;

  if(bitsIn){
    if(t < 128)
      *(uint4*)&MB[t*4] = *(const uint4*)&bitsIn[(size_t)(gr0 + t)*(N_T/32) + (gc0 >> 5)];
  } else {
    int mb = *flag;
    stage_mask_raw(maskp, mb, gr0, gc0, MB, t);
  }

  f32x4 acc[4][4] = {};
  qk_gemm(et16, eq16, gc0, gr0, t, SM, acc);

  const float sc = 0.08838834764831845f;   // 1/sqrt(128)
  #pragma unroll
  for(int n=0;n<4;n++){
    int q = wc*64 + n*16 + fr;
    float s = 0.f;
    #pragma unroll
    for(int m=0;m<4;m++){
      unsigned wb = MB[q*4 + wr*2 + (m>>1)];
      int off = ((m&1)<<4) | (kg0<<2);
      s += ((wb>>(off+0))&1u) ? __expf(acc[m][n][0]*sc) : 0.f;
      s += ((wb>>(off+1))&1u) ? __expf(acc[m][n][1]*sc) : 0.f;
      s += ((wb>>(off+2))&1u) ? __expf(acc[m][n][2]*sc) : 0.f;
      s += ((wb>>(off+3))&1u) ? __expf(acc[m][n][3]*sc) : 0.f;
    }
    s += __shfl_xor(s, 16);
    s += __shfl_xor(s, 32);
    if(lane < 16) RS[q][wr] = s;
  }
  __syncthreads();
  if(t < 128) atomicAdd(&rowsum[gr0 + t], RS[t][0] + RS[t][1]);
}

// ---------------- attention pass B: recompute, normalize, direct float4 store ----------------
__global__ __launch_bounds__(256,4) void attout_k(
    const ushort* __restrict__ eq16, const ushort* __restrict__ et16,
    const void* __restrict__ maskp, const int* __restrict__ flag,
    const unsigned* __restrict__ bitsIn, const float* __restrict__ rowsum,
    float* __restrict__ out){
  __shared__ ushort SM[2*128*64];       // 32 KB
  __shared__ __align__(16) unsigned MB[512];
  __shared__ float IRS[128];
  int t = threadIdx.x;
  int gc0 = blockIdx.x * 128;
  int gr0 = blockIdx.y * 128;
  int lane = t & 63;
  int w = t >> 6;
  int wr = w >> 1, wc = w & 1;
  int fr = lane & 15, kg0 = lane >> 4;

  if(bitsIn){
    if(t < 128)
      *(uint4*)&MB[t*4] = *(const uint4*)&bitsIn[(size_t)(gr0 + t)*(N_T/32) + (gc0 >> 5)];
  } else {
    int mb = *flag;
    stage_mask_raw(maskp, mb, gr0, gc0, MB, t);
  }
  if(t < 128) IRS[t] = 1.0f / rowsum[gr0 + t];

  f32x4 acc[4][4] = {};
  qk_gemm(et16, eq16, gc0, gr0, t, SM, acc);

  const float sc = 0.08838834764831845f;
  #pragma unroll
  for(int n=0;n<4;n++){
    int q = wc*64 + n*16 + fr;
    float ir = IRS[q];
    size_t rb = (size_t)(gr0 + q)*N_T + gc0 + wr*64;
    #pragma unroll
    for(int m=0;m<4;m++){
      unsigned wb = MB[q*4 + wr*2 + (m>>1)];
      int off = ((m&1)<<4) | (kg0<<2);
      float4 o;
      o.x = ((wb>>(off+0))&1u) ? __expf(acc[m][n][0]*sc)*ir : 0.f;
      o.y = ((wb>>(off+1))&1u) ? __expf(acc[m][n][1]*sc)*ir : 0.f;
      o.z = ((wb>>(off+2))&1u) ? __expf(acc[m][n][2]*sc)*ir : 0.f;
      o.w = ((wb>>(off+3))&1u) ? __expf(acc[m][n][3]*sc)*ir : 0.f;
      *(float4*)&out[rb + m*16 + (kg0<<2)] = o;
    }
  }
}

// ---------------- host launch ----------------
extern "C" void kernel_launch(void* const* d_in, const int* in_sizes, int n_in,
                              void* d_out, int out_size, void* d_ws, size_t ws_size,
                              hipStream_t stream){
  const int* tx  = (const int*)d_in[0];
  const int* qx  = (const int*)d_in[1];
  const int* te  = (const int*)d_in[2];
  const int* qe  = (const int*)d_in[3];
  const void* mask = d_in[4];
  const float* emb = (const float*)d_in[5];
  const float* Wl  = (const float*)d_in[6];
  const float* bl  = (const float*)d_in[7];
  const float* Wr  = (const float*)d_in[8];
  float* out = (float*)d_out;

  // ws layout: fp16 features + rowsum + flag (+ bit-mask at 19MB)
  ushort* et16 = (ushort*)d_ws;                       // N_T*H (8 MB)
  ushort* eq16 = et16 + (size_t)N_T*H;                // N_Q*H (1 MB)
  float* rowsum = (float*)(eq16 + (size_t)N_Q*H);
  int*   flag   = (int*)(rowsum + N_Q);
  bool useBits = ws_size >= ((size_t)37 << 20);
  unsigned* bits = useBits ? (unsigned*)((char*)d_ws + ((size_t)19 << 20)) : nullptr;

  // phase-1 scratch inside d_out (512MB; fully overwritten by attout at the end)
  char* S = (char*)d_out;
  ushort* xt0  = (ushort*)(S);                         // 8 MB
  ushort* xt1  = (ushort*)(S + 8388608);               // 8 MB
  ushort* aggt = (ushort*)(S + 16777216);              // 8 MB
  ushort* xq0  = (ushort*)(S + 25165824);              // 1 MB
  ushort* xq1  = (ushort*)(S + 26214400);              // 1 MB
  ushort* aggq = (ushort*)(S + 27262976);              // 1 MB
  int*   cnt_t = (int*)(S + 28311552);
  int*   rp_t  = cnt_t + N_T;
  int*   pos_t = rp_t + N_T + 1;
  int*   csr_t = pos_t + N_T;
  int*   cnt_q = csr_t + E_T;
  int*   rp_q  = cnt_q + N_Q;
  int*   pos_q = rp_q + N_Q + 1;
  int*   csr_q = pos_q + N_Q;

  zero_i32_k<<<(N_T+255)/256,256,0,stream>>>(cnt_t, N_T);
  zero_i32_k<<<(N_Q+255)/256,256,0,stream>>>(cnt_q, N_Q);
  zero_f32_k<<<(N_Q+255)/256,256,0,stream>>>(rowsum, N_Q);
  zero_i32_k<<<1,256,0,stream>>>(flag, 1);
  detect_mask_k<<<1,256,0,stream>>>((const unsigned*)mask, flag);
  if(bits) pack_mask_k<<<N_Q,256,0,stream>>>(mask, flag, bits);

  count_k<<<E_T/256,256,0,stream>>>(te+E_T, E_T, cnt_t);
  scan_k<<<1,1024,0,stream>>>(cnt_t, N_T, rp_t, pos_t);
  fill_k<<<E_T/256,256,0,stream>>>(te, te+E_T, E_T, pos_t, csr_t);
  count_k<<<E_Q/256,256,0,stream>>>(qe+E_Q, E_Q, cnt_q);
  scan_k<<<1,1024,0,stream>>>(cnt_q, N_Q, rp_q, pos_q);
  fill_k<<<E_Q/256,256,0,stream>>>(qe, qe+E_Q, E_Q, pos_q, csr_q);

  embed_k<<<N_T*16/256,256,0,stream>>>(tx, emb, xt0, N_T);
  embed_k<<<N_Q*16/256,256,0,stream>>>(qx, emb, xq0, N_Q);

  ushort* ct = xt0; ushort* nt = xt1;
  ushort* cq = xq0; ushort* nq = xq1;
  for(int l=0;l<NL;l++){
    int last = (l == NL-1);
    agg_k<<<N_T/4,256,0,stream>>>(ct, rp_t, csr_t, aggt, N_T);
    layer_k<<<N_T/128,256,0,stream>>>(aggt, ct, Wl+(size_t)l*H*H, Wr+(size_t)l*H*H,
                                      bl+(size_t)l*H, last ? et16 : nt, N_T);
    agg_k<<<N_Q/4,256,0,stream>>>(cq, rp_q, csr_q, aggq, N_Q);
    layer_k<<<N_Q/128,256,0,stream>>>(aggq, cq, Wl+(size_t)l*H*H, Wr+(size_t)l*H*H,
                                      bl+(size_t)l*H, last ? eq16 : nq, N_Q);
    ushort* tmp;
    tmp = ct; ct = nt; nt = tmp;
    tmp = cq; cq = nq; nq = tmp;
  }

  attsum_k<<<dim3(N_T/128, N_Q/128),256,0,stream>>>(eq16, et16, mask, flag, bits, rowsum);
  attout_k<<<dim3(N_T/128, N_Q/128),256,0,stream>>>(eq16, et16, mask, flag, bits, rowsum, out);
}

// Round 7
// 766.837 us; speedup vs baseline: 2.4995x; 1.3045x over previous
//
#include <hip/hip_runtime.h>
#include <stdint.h>

#define N_T 32768
#define N_Q 4096
#define E_T 1048576
#define E_Q 131072
#define H   128
#define NL  3

typedef float    f32x4 __attribute__((ext_vector_type(4)));
typedef _Float16 f16x8 __attribute__((ext_vector_type(8)));

__device__ __forceinline__ ushort f2h(float x){
  union{_Float16 h; ushort u;} c; c.h = (_Float16)x; return c.u;
}
__device__ __forceinline__ float h2f(unsigned u){
  union{ushort u; _Float16 h;} c; c.u = (ushort)u; return (float)c.h;
}

// ---------------- utility kernels ----------------
__global__ void zero_i32_k(int* p, int n){
  int i = blockIdx.x*blockDim.x + threadIdx.x;
  if(i<n) p[i]=0;
}
__global__ void zero_f32_k(float* p, int n){
  int i = blockIdx.x*blockDim.x + threadIdx.x;
  if(i<n) p[i]=0.f;
}

// classify mask dtype: flag bit0 -> uint8 bools, bit1 -> float32, 0 -> int32
__global__ void detect_mask_k(const unsigned* m, int* flag){
  int t = threadIdx.x;
  int f = 0;
  for(int j=t;j<4096;j+=256){
    unsigned v = m[j];
    if(v > 1u) f |= (v & 0xFEFEFEFEu) ? 2 : 1;
  }
  if(f) atomicOr(flag, f);
}

// ---------------- weight convert: f32 [Wl|Wr] -> fp16 hi + fp16 residual ----------------
__global__ void wcvt_k(const float* __restrict__ Wl, const float* __restrict__ Wr,
                       ushort* __restrict__ WH, ushort* __restrict__ WLo){
  int i = blockIdx.x*blockDim.x + threadIdx.x;   // NL*128*64 = 24576
  if(i >= NL*128*64) return;
  int k  = (i & 63) * 4;           // 0..252
  int c  = (i >> 6) & 127;
  int l  = i >> 13;
  const float* src = (k < 128)
      ? &Wl[((size_t)l*128 + c)*128 + k]
      : &Wr[((size_t)l*128 + c)*128 + (k-128)];
  float4 v = *(const float4*)src;
  ushort4 h, lo;
  h.x = f2h(v.x); lo.x = f2h(v.x - h2f(h.x));
  h.y = f2h(v.y); lo.y = f2h(v.y - h2f(h.y));
  h.z = f2h(v.z); lo.z = f2h(v.z - h2f(h.z));
  h.w = f2h(v.w); lo.w = f2h(v.w - h2f(h.w));
  size_t off = ((size_t)l*128 + c)*256 + k;
  *(ushort4*)&WH[off]  = h;
  *(ushort4*)&WLo[off] = lo;
}

// ---------------- CSR build ----------------
__global__ void count_k(const int* __restrict__ dst, int E, int* cnt){
  int i = blockIdx.x*blockDim.x + threadIdx.x;
  if(i<E) atomicAdd(&cnt[dst[i]], 1);
}

__global__ void scan_k(const int* __restrict__ cnt, int n, int* rp, int* pos){
  __shared__ int part[1024];
  int t = threadIdx.x;
  int chunk = (n + 1023) >> 10;
  int lo = t*chunk, hi = lo+chunk; if(hi>n) hi=n;
  int s = 0;
  for(int i=lo;i<hi;i++) s += cnt[i];
  part[t] = s;
  __syncthreads();
  for(int off=1; off<1024; off<<=1){
    int v = (t >= off) ? part[t-off] : 0;
    __syncthreads();
    part[t] += v;
    __syncthreads();
  }
  int run = (t==0) ? 0 : part[t-1];
  for(int i=lo;i<hi;i++){ rp[i]=run; pos[i]=run; run += cnt[i]; }
  if(t==0) rp[n] = part[1023];
}

__global__ void fill_k(const int* __restrict__ src, const int* __restrict__ dst,
                       int E, int* pos, int* csr){
  int i = blockIdx.x*blockDim.x + threadIdx.x;
  if(i<E){
    int p = atomicAdd(&pos[dst[i]], 1);
    csr[p] = src[i];
  }
}

// ---------------- embedding gather (f32 table -> fp16 features) ----------------
__global__ void embed_k(const int* __restrict__ idx, const float* __restrict__ emb,
                        ushort* __restrict__ out, int N){
  int i = blockIdx.x*blockDim.x + threadIdx.x;   // N*16 threads
  int n = i >> 4, c = i & 15;
  if(n < N){
    size_t eb = (size_t)idx[n]*32 + c*2;
    float4 v0 = ((const float4*)emb)[eb];
    float4 v1 = ((const float4*)emb)[eb+1];
    uint4 o;
    o.x = (unsigned)f2h(v0.x) | ((unsigned)f2h(v0.y)<<16);
    o.y = (unsigned)f2h(v0.z) | ((unsigned)f2h(v0.w)<<16);
    o.z = (unsigned)f2h(v1.x) | ((unsigned)f2h(v1.y)<<16);
    o.w = (unsigned)f2h(v1.z) | ((unsigned)f2h(v1.w)<<16);
    ((uint4*)out)[(size_t)n*16 + c] = o;
  }
}

// ---------------- segment mean (fp16 features, one wave per dst node) ----------------
__global__ void agg_k(const ushort* __restrict__ x, const int* __restrict__ rp,
                      const int* __restrict__ csr, ushort* __restrict__ agg, int N){
  int wid = (int)(((size_t)blockIdx.x*blockDim.x + threadIdx.x) >> 6);
  int lane = threadIdx.x & 63;
  if(wid >= N) return;
  const unsigned* xp = (const unsigned*)x;     // 2 fp16 per word
  int rs = rp[wid], re = rp[wid+1];
  float ax=0.f, ay=0.f, bx=0.f, by=0.f, cx=0.f, cy=0.f, dx=0.f, dy=0.f;
  int j = rs;
  for(; j+4 <= re; j+=4){
    int s0 = csr[j], s1 = csr[j+1], s2 = csr[j+2], s3 = csr[j+3];
    unsigned u0 = xp[(size_t)s0*64 + lane];
    unsigned u1 = xp[(size_t)s1*64 + lane];
    unsigned u2 = xp[(size_t)s2*64 + lane];
    unsigned u3 = xp[(size_t)s3*64 + lane];
    ax += h2f(u0 & 0xFFFFu); ay += h2f(u0 >> 16);
    bx += h2f(u1 & 0xFFFFu); by += h2f(u1 >> 16);
    cx += h2f(u2 & 0xFFFFu); cy += h2f(u2 >> 16);
    dx += h2f(u3 & 0xFFFFu); dy += h2f(u3 >> 16);
  }
  for(; j < re; j++){
    unsigned u = xp[(size_t)csr[j]*64 + lane];
    ax += h2f(u & 0xFFFFu); ay += h2f(u >> 16);
  }
  float sx = (ax + bx) + (cx + dx);
  float sy = (ay + by) + (cy + dy);
  int c = re - rs; if(c < 1) c = 1;
  float inv = 1.0f / (float)c;
  ((unsigned*)agg)[(size_t)wid*64 + lane] =
      (unsigned)f2h(sx*inv) | ((unsigned)f2h(sy*inv) << 16);
}

// ---------------- layer GEMM (MFMA): out = elu([agg|x] @ [Wl|Wr]^T + bl) ----------------
// 128x128 tile, 4 waves 2x2, K=256 in 4 chunks of 64; W in fp16 hi+lo (f32-equivalent)
__global__ __launch_bounds__(256,3) void layer_k(
    const ushort* __restrict__ agg, const ushort* __restrict__ x,
    const ushort* __restrict__ WH, const ushort* __restrict__ WLo,
    const float* __restrict__ bl, ushort* __restrict__ out16){
  __shared__ ushort SM3[3*128*64];     // SA | SH | SL (48 KB); SA+SH reused as LT
  ushort* SA = SM3;
  ushort* SH = SM3 + 8192;
  ushort* SL = SM3 + 16384;
  int t = threadIdx.x;
  int r0g = blockIdx.x * 128;
  int lane = t & 63;
  int w = t >> 6;
  int wr = w >> 1, wc = w & 1;
  int fr = lane & 15, kg0 = lane >> 4;
  f32x4 acc[4][4] = {};
  for(int kt=0; kt<4; kt++){
    __syncthreads();
    const ushort* A = (kt < 2) ? agg : x;
    int ko = (kt & 1) * 64;
    #pragma unroll
    for(int it=0; it<4; it++){
      int idx = t + it*256;            // 0..1023
      int row = idx >> 3, k8 = idx & 7;
      int sw = (k8 ^ (row & 7)) * 8;
      *(uint4*)&SA[row*64 + sw] = *(const uint4*)&A[(size_t)(r0g+row)*H + ko + k8*8];
      *(uint4*)&SH[row*64 + sw] = *(const uint4*)&WH[row*256 + kt*64 + k8*8];
      *(uint4*)&SL[row*64 + sw] = *(const uint4*)&WLo[row*256 + kt*64 + k8*8];
    }
    __syncthreads();
    #pragma unroll
    for(int s=0; s<2; s++){
      int kg = s*4 + kg0;
      f16x8 a[4], bh[4], blo[4];
      #pragma unroll
      for(int m=0;m<4;m++){
        int ar = wr*64 + m*16 + fr;
        a[m] = *(const f16x8*)&SA[ar*64 + ((kg ^ (ar & 7)) << 3)];
      }
      #pragma unroll
      for(int n=0;n<4;n++){
        int bc = wc*64 + n*16 + fr;
        int ib = bc*64 + ((kg ^ (bc & 7)) << 3);
        bh[n]  = *(const f16x8*)&SH[ib];
        blo[n] = *(const f16x8*)&SL[ib];
      }
      #pragma unroll
      for(int m=0;m<4;m++)
        #pragma unroll
        for(int n=0;n<4;n++){
          acc[m][n] = __builtin_amdgcn_mfma_f32_16x16x32_f16(a[m], bh[n],  acc[m][n], 0,0,0);
          acc[m][n] = __builtin_amdgcn_mfma_f32_16x16x32_f16(a[m], blo[n], acc[m][n], 0,0,0);
        }
    }
  }
  __syncthreads();
  // bias + ELU + fp16, transpose through LDS, coalesced store
  ushort* LT = SM3;                    // 128*128 ushort = 32 KB
  #pragma unroll
  for(int n=0;n<4;n++){
    int c = wc*64 + n*16 + fr;
    float b = bl[c];
    #pragma unroll
    for(int m=0;m<4;m++){
      int r = wr*64 + m*16 + kg0*4;
      #pragma unroll
      for(int reg=0;reg<4;reg++){
        float v = acc[m][n][reg] + b;
        v = (v > 0.f) ? v : expm1f(v);
        LT[(r+reg)*128 + c] = f2h(v);
      }
    }
  }
  __syncthreads();
  #pragma unroll
  for(int i=0;i<8;i++){
    int idx = t + i*256;               // 0..2047
    int row = idx >> 4, c8 = idx & 15;
    *(uint4*)&out16[(size_t)(r0g+row)*H + c8*8] = *(uint4*)&LT[row*128 + c8*8];
  }
}

// ---------------- attention helpers ----------------
__device__ __forceinline__ unsigned nib8(unsigned x, unsigned y){
  unsigned r = (x & 0xFu) | ((x>>4)&0xF0u) | ((x>>8)&0xF00u) | ((x>>12)&0xF000u);
  unsigned s = (y & 0xFu) | ((y>>4)&0xF0u) | ((y>>8)&0xF00u) | ((y>>12)&0xF000u);
  return r | (s<<16);
}
__device__ __forceinline__ unsigned pk4(unsigned u){
  return ((u & 0xFFu)       ? 1u : 0u) | ((u & 0xFF00u)     ? 2u : 0u)
       | ((u & 0xFF0000u)   ? 4u : 0u) | ((u & 0xFF000000u) ? 8u : 0u);
}

// stage 128x128 raw mask tile -> MB[512] packed bits (coalesced, no ballot).
// NB = 4KB nibble staging (aliased onto SM). Optionally emits bits to global.
__device__ __forceinline__ void stage_mask_tile(const void* maskp, int mb,
    int gr0, int gc0, unsigned* MB, uint8_t* NB, unsigned* bitsOut, int t){
  if(mb & 2){
    const float* base = (const float*)maskp;
    #pragma unroll
    for(int i=0;i<16;i++){
      int idx = i*256 + t;             // float4 index: row = idx>>5, group = idx&31
      int row = idx >> 5, c4 = idx & 31;
      float4 v = *(const float4*)&base[(size_t)(gr0+row)*N_T + gc0 + c4*4];
      NB[row*32 + c4] = (uint8_t)((unsigned)(v.x!=0.f) | ((unsigned)(v.y!=0.f)<<1)
                                | ((unsigned)(v.z!=0.f)<<2) | ((unsigned)(v.w!=0.f)<<3));
    }
  } else if(mb & 1){
    const uint8_t* base = (const uint8_t*)maskp;
    #pragma unroll
    for(int i=0;i<16;i++){
      int idx = i*256 + t;             // word index: row = idx>>5, word = idx&31
      int row = idx >> 5, c4 = idx & 31;
      unsigned u = *(const unsigned*)&base[(size_t)(gr0+row)*N_T + gc0 + c4*4];
      NB[row*32 + c4] = (uint8_t)pk4(u);
    }
  } else {
    const int* base = (const int*)maskp;
    #pragma unroll
    for(int i=0;i<16;i++){
      int idx = i*256 + t;
      int row = idx >> 5, c4 = idx & 31;
      int4 v = *(const int4*)&base[(size_t)(gr0+row)*N_T + gc0 + c4*4];
      NB[row*32 + c4] = (uint8_t)((unsigned)(v.x!=0) | ((unsigned)(v.y!=0)<<1)
                                | ((unsigned)(v.z!=0)<<2) | ((unsigned)(v.w!=0)<<3));
    }
  }
  __syncthreads();
  if(t < 128){
    uint4 a = *(const uint4*)&NB[t*32];
    uint4 b = *(const uint4*)&NB[t*32 + 16];
    unsigned w0 = nib8(a.x, a.y), w1 = nib8(a.z, a.w);
    unsigned w2 = nib8(b.x, b.y), w3 = nib8(b.z, b.w);
    MB[t*4]   = w0; MB[t*4+1] = w1;
    MB[t*4+2] = w2; MB[t*4+3] = w3;
    if(bitsOut){
      uint4 o; o.x=w0; o.y=w1; o.z=w2; o.w=w3;
      *(uint4*)&bitsOut[(size_t)(gr0 + t)*(N_T/32) + (gc0 >> 5)] = o;
    }
  }
}

// fp16 S^T GEMM core: A = et (M=target), B = eq (N=query). 128x128 tile, 4 waves.
// acc[m][n]: t_local = wr*64+m*16+kg0*4+reg, q_local = wc*64+n*16+fr
__device__ __forceinline__ void qk_gemm(
    const ushort* __restrict__ A16, const ushort* __restrict__ B16,
    int abase, int bbase, int t, ushort* SM, f32x4 (&acc)[4][4]){
  ushort* AB = SM;            // [128][64] swizzled
  ushort* BB = SM + 8192;
  int lane = t & 63;
  int w = t >> 6;
  int wr = w >> 1, wc = w & 1;
  int fr = lane & 15, kg0 = lane >> 4;
  for(int kt=0; kt<2; kt++){
    __syncthreads();
    #pragma unroll
    for(int it=0; it<4; it++){
      int idx = t + it*256;          // 0..1023
      int row = idx >> 3, k8 = idx & 7;
      int sw = (k8 ^ (row & 7)) * 8;
      *(uint4*)&AB[row*64 + sw] = *(const uint4*)&A16[(size_t)(abase+row)*H + kt*64 + k8*8];
      *(uint4*)&BB[row*64 + sw] = *(const uint4*)&B16[(size_t)(bbase+row)*H + kt*64 + k8*8];
    }
    __syncthreads();
    #pragma unroll
    for(int s=0; s<2; s++){
      int kg = s*4 + kg0;
      f16x8 a[4], b[4];
      #pragma unroll
      for(int m=0;m<4;m++){
        int ar = wr*64 + m*16 + fr;
        a[m] = *(const f16x8*)&AB[ar*64 + ((kg ^ (ar & 7)) << 3)];
      }
      #pragma unroll
      for(int n=0;n<4;n++){
        int bc = wc*64 + n*16 + fr;
        b[n] = *(const f16x8*)&BB[bc*64 + ((kg ^ (bc & 7)) << 3)];
      }
      #pragma unroll
      for(int m=0;m<4;m++)
        #pragma unroll
        for(int n=0;n<4;n++)
          acc[m][n] = __builtin_amdgcn_mfma_f32_16x16x32_f16(a[m], b[n], acc[m][n], 0,0,0);
    }
  }
}

// ---------------- attention pass A: raw mask -> bits, GEMM, rowsums ----------------
__global__ __launch_bounds__(256,4) void attsum_k(
    const ushort* __restrict__ eq16, const ushort* __restrict__ et16,
    const void* __restrict__ maskp, const int* __restrict__ flag,
    unsigned* __restrict__ bitsOut, float* __restrict__ rowsum){
  __shared__ ushort SM[2*128*64];       // 32 KB (first 4KB aliased as nibble staging)
  __shared__ __align__(16) unsigned MB[512];
  __shared__ float RS[128][2];
  int t = threadIdx.x;
  int gc0 = blockIdx.x * 128;   // target base
  int gr0 = blockIdx.y * 128;   // query base
  int lane = t & 63;
  int w = t >> 6;
  int wr = w >> 1, wc = w & 1;
  int fr = lane & 15, kg0 = lane >> 4;

  int mb = *flag;
  stage_mask_tile(maskp, mb, gr0, gc0, MB, (uint8_t*)SM, bitsOut, t);

  f32x4 acc[4][4] = {};
  qk_gemm(et16, eq16, gc0, gr0, t, SM, acc);

  const float sc = 0.08838834764831845f;   // 1/sqrt(128)
  #pragma unroll
  for(int n=0;n<4;n++){
    int q = wc*64 + n*16 + fr;
    float s = 0.f;
    #pragma unroll
    for(int m=0;m<4;m++){
      unsigned wb = MB[q*4 + wr*2 + (m>>1)];
      int off = ((m&1)<<4) | (kg0<<2);
      s += ((wb>>(off+0))&1u) ? __expf(acc[m][n][0]*sc) : 0.f;
      s += ((wb>>(off+1))&1u) ? __expf(acc[m][n][1]*sc) : 0.f;
      s += ((wb>>(off+2))&1u) ? __expf(acc[m][n][2]*sc) : 0.f;
      s += ((wb>>(off+3))&1u) ? __expf(acc[m][n][3]*sc) : 0.f;
    }
    s += __shfl_xor(s, 16);
    s += __shfl_xor(s, 32);
    if(lane < 16) RS[q][wr] = s;
  }
  __syncthreads();
  if(t < 128) atomicAdd(&rowsum[gr0 + t], RS[t][0] + RS[t][1]);
}

// ---------------- attention pass B: recompute, normalize, direct float4 store ----------------
__global__ __launch_bounds__(256,4) void attout_k(
    const ushort* __restrict__ eq16, const ushort* __restrict__ et16,
    const void* __restrict__ maskp, const int* __restrict__ flag,
    const unsigned* __restrict__ bitsIn, const float* __restrict__ rowsum,
    float* __restrict__ out){
  __shared__ ushort SM[2*128*64];
  __shared__ __align__(16) unsigned MB[512];
  __shared__ float IRS[128];
  int t = threadIdx.x;
  int gc0 = blockIdx.x * 128;
  int gr0 = blockIdx.y * 128;
  int lane = t & 63;
  int w = t >> 6;
  int wr = w >> 1, wc = w & 1;
  int fr = lane & 15, kg0 = lane >> 4;

  if(bitsIn){
    if(t < 128)
      *(uint4*)&MB[t*4] = *(const uint4*)&bitsIn[(size_t)(gr0 + t)*(N_T/32) + (gc0 >> 5)];
  } else {
    int mb = *flag;
    stage_mask_tile(maskp, mb, gr0, gc0, MB, (uint8_t*)SM, nullptr, t);
  }
  if(t < 128) IRS[t] = 1.0f / rowsum[gr0 + t];

  f32x4 acc[4][4] = {};
  qk_gemm(et16, eq16, gc0, gr0, t, SM, acc);

  const float sc = 0.08838834764831845f;
  #pragma unroll
  for(int n=0;n<4;n++){
    int q = wc*64 + n*16 + fr;
    float ir = IRS[q];
    size_t rb = (size_t)(gr0 + q)*N_T + gc0 + wr*64;
    #pragma unroll
    for(int m=0;m<4;m++){
      unsigned wb = MB[q*4 + wr*2 + (m>>1)];
      int off = ((m&1)<<4) | (kg0<<2);
      float4 o;
      o.x = ((wb>>(off+0))&1u) ? __expf(acc[m][n][0]*sc)*ir : 0.f;
      o.y = ((wb>>(off+1))&1u) ? __expf(acc[m][n][1]*sc)*ir : 0.f;
      o.z = ((wb>>(off+2))&1u) ? __expf(acc[m][n][2]*sc)*ir : 0.f;
      o.w = ((wb>>(off+3))&1u) ? __expf(acc[m][n][3]*sc)*ir : 0.f;
      *(float4*)&out[rb + m*16 + (kg0<<2)] = o;
    }
  }
}

// ---------------- host launch ----------------
extern "C" void kernel_launch(void* const* d_in, const int* in_sizes, int n_in,
                              void* d_out, int out_size, void* d_ws, size_t ws_size,
                              hipStream_t stream){
  const int* tx  = (const int*)d_in[0];
  const int* qx  = (const int*)d_in[1];
  const int* te  = (const int*)d_in[2];
  const int* qe  = (const int*)d_in[3];
  const void* mask = d_in[4];
  const float* emb = (const float*)d_in[5];
  const float* Wl  = (const float*)d_in[6];
  const float* bl  = (const float*)d_in[7];
  const float* Wr  = (const float*)d_in[8];
  float* out = (float*)d_out;

  // ws layout: fp16 features @0, rowsum/flag @~9MB, fp16 weights @10MB, bits @19MB
  ushort* et16 = (ushort*)d_ws;                       // N_T*H (8 MB)
  ushort* eq16 = et16 + (size_t)N_T*H;                // N_Q*H (1 MB)
  float* rowsum = (float*)(eq16 + (size_t)N_Q*H);
  int*   flag   = (int*)(rowsum + N_Q);
  ushort* WH  = (ushort*)((char*)d_ws + ((size_t)10 << 20));   // NL*128*256 (192 KB)
  ushort* WLo = WH + (size_t)NL*128*256;
  bool useBits = ws_size >= ((size_t)37 << 20);
  unsigned* bits = useBits ? (unsigned*)((char*)d_ws + ((size_t)19 << 20)) : nullptr;

  // phase-1 scratch inside d_out (512MB; fully overwritten by attout at the end)
  char* S = (char*)d_out;
  ushort* xt0  = (ushort*)(S);                         // 8 MB
  ushort* xt1  = (ushort*)(S + 8388608);               // 8 MB
  ushort* aggt = (ushort*)(S + 16777216);              // 8 MB
  ushort* xq0  = (ushort*)(S + 25165824);              // 1 MB
  ushort* xq1  = (ushort*)(S + 26214400);              // 1 MB
  ushort* aggq = (ushort*)(S + 27262976);              // 1 MB
  int*   cnt_t = (int*)(S + 28311552);
  int*   rp_t  = cnt_t + N_T;
  int*   pos_t = rp_t + N_T + 1;
  int*   csr_t = pos_t + N_T;
  int*   cnt_q = csr_t + E_T;
  int*   rp_q  = cnt_q + N_Q;
  int*   pos_q = rp_q + N_Q + 1;
  int*   csr_q = pos_q + N_Q;

  zero_i32_k<<<(N_T+255)/256,256,0,stream>>>(cnt_t, N_T);
  zero_i32_k<<<(N_Q+255)/256,256,0,stream>>>(cnt_q, N_Q);
  zero_f32_k<<<(N_Q+255)/256,256,0,stream>>>(rowsum, N_Q);
  zero_i32_k<<<1,256,0,stream>>>(flag, 1);
  detect_mask_k<<<1,256,0,stream>>>((const unsigned*)mask, flag);
  wcvt_k<<<96,256,0,stream>>>(Wl, Wr, WH, WLo);

  count_k<<<E_T/256,256,0,stream>>>(te+E_T, E_T, cnt_t);
  scan_k<<<1,1024,0,stream>>>(cnt_t, N_T, rp_t, pos_t);
  fill_k<<<E_T/256,256,0,stream>>>(te, te+E_T, E_T, pos_t, csr_t);
  count_k<<<E_Q/256,256,0,stream>>>(qe+E_Q, E_Q, cnt_q);
  scan_k<<<1,1024,0,stream>>>(cnt_q, N_Q, rp_q, pos_q);
  fill_k<<<E_Q/256,256,0,stream>>>(qe, qe+E_Q, E_Q, pos_q, csr_q);

  embed_k<<<N_T*16/256,256,0,stream>>>(tx, emb, xt0, N_T);
  embed_k<<<N_Q*16/256,256,0,stream>>>(qx, emb, xq0, N_Q);

  ushort* ct = xt0; ushort* nt = xt1;
  ushort* cq = xq0; ushort* nq = xq1;
  for(int l=0;l<NL;l++){
    int last = (l == NL-1);
    const ushort* wh = WH  + (size_t)l*128*256;
    const ushort* wl = WLo + (size_t)l*128*256;
    agg_k<<<N_T/4,256,0,stream>>>(ct, rp_t, csr_t, aggt, N_T);
    layer_k<<<N_T/128,256,0,stream>>>(aggt, ct, wh, wl, bl+(size_t)l*H, last ? et16 : nt);
    agg_k<<<N_Q/4,256,0,stream>>>(cq, rp_q, csr_q, aggq, N_Q);
    layer_k<<<N_Q/128,256,0,stream>>>(aggq, cq, wh, wl, bl+(size_t)l*H, last ? eq16 : nq);
    ushort* tmp;
    tmp = ct; ct = nt; nt = tmp;
    tmp = cq; cq = nq; nq = tmp;
  }

  attsum_k<<<dim3(N_T/128, N_Q/128),256,0,stream>>>(eq16, et16, mask, flag, bits, rowsum);
  attout_k<<<dim3(N_T/128, N_Q/128),256,0,stream>>>(eq16, et16, mask, flag, bits, rowsum, out);
}

// Round 9
// 711.070 us; speedup vs baseline: 2.6955x; 1.0784x over previous
//
#include <hip/hip_runtime.h>
#include <stdint.h>

#define N_T 32768
#define N_Q 4096
#define E_T 1048576
#define E_Q 131072
#define H   128
#define NL  3
#define VOCAB 1001

typedef float    f32x4 __attribute__((ext_vector_type(4)));
typedef int      i32x4 __attribute__((ext_vector_type(4)));
typedef unsigned u32x4 __attribute__((ext_vector_type(4)));
typedef _Float16 f16x8 __attribute__((ext_vector_type(8)));

__device__ __forceinline__ ushort f2h(float x){
  union{_Float16 h; ushort u;} c; c.h = (_Float16)x; return c.u;
}
__device__ __forceinline__ float h2f(unsigned u){
  union{ushort u; _Float16 h;} c; c.u = (ushort)u; return (float)c.h;
}

// ---------------- utility kernels ----------------
__global__ void zero_i32_k(int* p, int n){
  int i = blockIdx.x*blockDim.x + threadIdx.x;
  if(i<n) p[i]=0;
}
__global__ void zero_f32_k(float* p, int n){
  int i = blockIdx.x*blockDim.x + threadIdx.x;
  if(i<n) p[i]=0.f;
}

// classify mask dtype: flag bit0 -> uint8 bools, bit1 -> float32, 0 -> int32
__global__ void detect_mask_k(const unsigned* m, int* flag){
  int t = threadIdx.x;
  int f = 0;
  for(int j=t;j<4096;j+=256){
    unsigned v = m[j];
    if(v > 1u) f |= (v & 0xFEFEFEFEu) ? 2 : 1;
  }
  if(f) atomicOr(flag, f);
}

// ---------------- weight convert: f32 [Wl|Wr] -> fp16 hi + fp16 residual ----------------
__global__ void wcvt_k(const float* __restrict__ Wl, const float* __restrict__ Wr,
                       ushort* __restrict__ WH, ushort* __restrict__ WLo){
  int i = blockIdx.x*blockDim.x + threadIdx.x;   // NL*128*64 = 24576
  if(i >= NL*128*64) return;
  int k  = (i & 63) * 4;           // 0..252
  int c  = (i >> 6) & 127;
  int l  = i >> 13;
  const float* src = (k < 128)
      ? &Wl[((size_t)l*128 + c)*128 + k]
      : &Wr[((size_t)l*128 + c)*128 + (k-128)];
  float4 v = *(const float4*)src;
  ushort4 h, lo;
  h.x = f2h(v.x); lo.x = f2h(v.x - h2f(h.x));
  h.y = f2h(v.y); lo.y = f2h(v.y - h2f(h.y));
  h.z = f2h(v.z); lo.z = f2h(v.z - h2f(h.z));
  h.w = f2h(v.w); lo.w = f2h(v.w - h2f(h.w));
  size_t off = ((size_t)l*128 + c)*256 + k;
  *(ushort4*)&WH[off]  = h;
  *(ushort4*)&WLo[off] = lo;
}

// ---------------- embedding table convert: f32 -> fp16 (256 KB, L2-resident) ----------------
__global__ void ecvt_k(const float* __restrict__ e, ushort* __restrict__ o){
  int i = blockIdx.x*blockDim.x + threadIdx.x;   // VOCAB*H/8 = 16016
  if(i >= VOCAB*H/8) return;
  float4 v0 = ((const float4*)e)[(size_t)i*2];
  float4 v1 = ((const float4*)e)[(size_t)i*2 + 1];
  uint4 u;
  u.x = (unsigned)f2h(v0.x) | ((unsigned)f2h(v0.y)<<16);
  u.y = (unsigned)f2h(v0.z) | ((unsigned)f2h(v0.w)<<16);
  u.z = (unsigned)f2h(v1.x) | ((unsigned)f2h(v1.y)<<16);
  u.w = (unsigned)f2h(v1.z) | ((unsigned)f2h(v1.w)<<16);
  ((uint4*)o)[i] = u;
}

// ---------------- CSR build ----------------
__global__ void count_k(const int* __restrict__ dst, int E, int* cnt){
  int i = blockIdx.x*blockDim.x + threadIdx.x;
  if(i<E) atomicAdd(&cnt[dst[i]], 1);
}

__global__ void scan_k(const int* __restrict__ cnt, int n, int* rp, int* pos){
  __shared__ int part[1024];
  int t = threadIdx.x;
  int chunk = (n + 1023) >> 10;
  int lo = t*chunk, hi = lo+chunk; if(hi>n) hi=n;
  int s = 0;
  for(int i=lo;i<hi;i++) s += cnt[i];
  part[t] = s;
  __syncthreads();
  for(int off=1; off<1024; off<<=1){
    int v = (t >= off) ? part[t-off] : 0;
    __syncthreads();
    part[t] += v;
    __syncthreads();
  }
  int run = (t==0) ? 0 : part[t-1];
  for(int i=lo;i<hi;i++){ rp[i]=run; pos[i]=run; run += cnt[i]; }
  if(t==0) rp[n] = part[1023];
}

__global__ void fill_k(const int* __restrict__ src, const int* __restrict__ dst,
                       int E, int* pos, int* csr){
  int i = blockIdx.x*blockDim.x + threadIdx.x;
  if(i<E){
    int p = atomicAdd(&pos[dst[i]], 1);
    csr[p] = src[i];
  }
}

// ---------------- segment mean (fp16 features; layer0 reads emb16[nid[s]] from L2) ----------------
__global__ void agg_k(const ushort* __restrict__ x, const int* __restrict__ nid,
                      const ushort* __restrict__ emb16,
                      const int* __restrict__ rp, const int* __restrict__ csr,
                      ushort* __restrict__ agg, int N){
  int wid = (int)(((size_t)blockIdx.x*blockDim.x + threadIdx.x) >> 6);
  int lane = threadIdx.x & 63;
  if(wid >= N) return;
  const unsigned* xw = (const unsigned*)x;
  const unsigned* ew = (const unsigned*)emb16;
  int rs = rp[wid], re = rp[wid+1];
  float px[8], py[8];
  #pragma unroll
  for(int q=0;q<8;q++){ px[q]=0.f; py[q]=0.f; }
  int j = rs;
  if(nid){
    for(; j+8 <= re; j+=8){
      #pragma unroll
      for(int q=0;q<8;q++){
        unsigned u = ew[(size_t)nid[csr[j+q]]*64 + lane];
        px[q] += h2f(u & 0xFFFFu); py[q] += h2f(u >> 16);
      }
    }
    for(; j < re; j++){
      unsigned u = ew[(size_t)nid[csr[j]]*64 + lane];
      px[0] += h2f(u & 0xFFFFu); py[0] += h2f(u >> 16);
    }
  } else {
    for(; j+8 <= re; j+=8){
      #pragma unroll
      for(int q=0;q<8;q++){
        unsigned u = xw[(size_t)csr[j+q]*64 + lane];
        px[q] += h2f(u & 0xFFFFu); py[q] += h2f(u >> 16);
      }
    }
    for(; j < re; j++){
      unsigned u = xw[(size_t)csr[j]*64 + lane];
      px[0] += h2f(u & 0xFFFFu); py[0] += h2f(u >> 16);
    }
  }
  float sx = ((px[0]+px[1]) + (px[2]+px[3])) + ((px[4]+px[5]) + (px[6]+px[7]));
  float sy = ((py[0]+py[1]) + (py[2]+py[3])) + ((py[4]+py[5]) + (py[6]+py[7]));
  int c = re - rs; if(c < 1) c = 1;
  float inv = 1.0f / (float)c;
  ((unsigned*)agg)[(size_t)wid*64 + lane] =
      (unsigned)f2h(sx*inv) | ((unsigned)f2h(sy*inv) << 16);
}

// ---------------- layer GEMM (MFMA): out = elu([agg|x] @ [Wl|Wr]^T + bl) ----------------
// 128x128 tile, 4 waves 2x2, K=256 in 4 chunks of 64; W in fp16 hi+lo (f32-equivalent)
// x-side: layer0 reads emb16[nid[row]] directly (no materialized x).
__global__ __launch_bounds__(256,3) void layer_k(
    const ushort* __restrict__ agg, const ushort* __restrict__ xprev,
    const int* __restrict__ nid, const ushort* __restrict__ emb16,
    const ushort* __restrict__ WH, const ushort* __restrict__ WLo,
    const float* __restrict__ bl, ushort* __restrict__ out16){
  __shared__ ushort SM3[3*128*64];     // SA | SH | SL (48 KB); reused as LT
  ushort* SA = SM3;
  ushort* SH = SM3 + 8192;
  ushort* SL = SM3 + 16384;
  int t = threadIdx.x;
  int r0g = blockIdx.x * 128;
  int lane = t & 63;
  int w = t >> 6;
  int wr = w >> 1, wc = w & 1;
  int fr = lane & 15, kg0 = lane >> 4;
  f32x4 acc[4][4] = {};
  for(int kt=0; kt<4; kt++){
    __syncthreads();
    int ko = (kt & 1) * 64;
    #pragma unroll
    for(int it=0; it<4; it++){
      int idx = t + it*256;            // 0..1023
      int row = idx >> 3, k8 = idx & 7;
      int sw = (k8 ^ (row & 7)) * 8;
      uint4 av;
      if(kt < 2){
        av = *(const uint4*)&agg[(size_t)(r0g+row)*H + ko + k8*8];
      } else if(nid){
        av = *(const uint4*)&emb16[(size_t)nid[r0g+row]*H + ko + k8*8];
      } else {
        av = *(const uint4*)&xprev[(size_t)(r0g+row)*H + ko + k8*8];
      }
      *(uint4*)&SA[row*64 + sw] = av;
      *(uint4*)&SH[row*64 + sw] = *(const uint4*)&WH[row*256 + kt*64 + k8*8];
      *(uint4*)&SL[row*64 + sw] = *(const uint4*)&WLo[row*256 + kt*64 + k8*8];
    }
    __syncthreads();
    #pragma unroll
    for(int s=0; s<2; s++){
      int kg = s*4 + kg0;
      f16x8 a[4], bh[4], blo[4];
      #pragma unroll
      for(int m=0;m<4;m++){
        int ar = wr*64 + m*16 + fr;
        a[m] = *(const f16x8*)&SA[ar*64 + ((kg ^ (ar & 7)) << 3)];
      }
      #pragma unroll
      for(int n=0;n<4;n++){
        int bc = wc*64 + n*16 + fr;
        int ib = bc*64 + ((kg ^ (bc & 7)) << 3);
        bh[n]  = *(const f16x8*)&SH[ib];
        blo[n] = *(const f16x8*)&SL[ib];
      }
      #pragma unroll
      for(int m=0;m<4;m++)
        #pragma unroll
        for(int n=0;n<4;n++){
          acc[m][n] = __builtin_amdgcn_mfma_f32_16x16x32_f16(a[m], bh[n],  acc[m][n], 0,0,0);
          acc[m][n] = __builtin_amdgcn_mfma_f32_16x16x32_f16(a[m], blo[n], acc[m][n], 0,0,0);
        }
    }
  }
  __syncthreads();
  // bias + ELU + fp16, transpose through LDS, coalesced store
  ushort* LT = SM3;                    // 128*128 ushort = 32 KB
  #pragma unroll
  for(int n=0;n<4;n++){
    int c = wc*64 + n*16 + fr;
    float b = bl[c];
    #pragma unroll
    for(int m=0;m<4;m++){
      int r = wr*64 + m*16 + kg0*4;
      #pragma unroll
      for(int reg=0;reg<4;reg++){
        float v = acc[m][n][reg] + b;
        v = (v > 0.f) ? v : expm1f(v);
        LT[(r+reg)*128 + c] = f2h(v);
      }
    }
  }
  __syncthreads();
  #pragma unroll
  for(int i=0;i<8;i++){
    int idx = t + i*256;               // 0..2047
    int row = idx >> 4, c8 = idx & 15;
    *(uint4*)&out16[(size_t)(r0g+row)*H + c8*8] = *(uint4*)&LT[row*128 + c8*8];
  }
}

// ---------------- attention helpers ----------------
__device__ __forceinline__ unsigned nib8(unsigned x, unsigned y){
  unsigned r = (x & 0xFu) | ((x>>4)&0xF0u) | ((x>>8)&0xF00u) | ((x>>12)&0xF000u);
  unsigned s = (y & 0xFu) | ((y>>4)&0xF0u) | ((y>>8)&0xF00u) | ((y>>12)&0xF000u);
  return r | (s<<16);
}
__device__ __forceinline__ unsigned pk4(unsigned u){
  return ((u & 0xFFu)       ? 1u : 0u) | ((u & 0xFF00u)     ? 2u : 0u)
       | ((u & 0xFF0000u)   ? 4u : 0u) | ((u & 0xFF000000u) ? 8u : 0u);
}

// stage 128x128 raw mask tile -> MB[512] packed bits (coalesced, NT loads, no ballot).
__device__ __forceinline__ void stage_mask_tile(const void* maskp, int mb,
    int gr0, int gc0, unsigned* MB, uint8_t* NB, unsigned* bitsOut, int t){
  if(mb & 2){
    const f32x4* base = (const f32x4*)maskp;
    #pragma unroll
    for(int i=0;i<16;i++){
      int idx = i*256 + t;
      int row = idx >> 5, c4 = idx & 31;
      f32x4 v = __builtin_nontemporal_load(
          &base[((size_t)(gr0+row)*N_T + gc0) / 4 + c4]);
      NB[row*32 + c4] = (uint8_t)((unsigned)(v[0]!=0.f) | ((unsigned)(v[1]!=0.f)<<1)
                                | ((unsigned)(v[2]!=0.f)<<2) | ((unsigned)(v[3]!=0.f)<<3));
    }
  } else if(mb & 1){
    const uint8_t* base = (const uint8_t*)maskp;
    #pragma unroll
    for(int i=0;i<16;i++){
      int idx = i*256 + t;
      int row = idx >> 5, c4 = idx & 31;
      unsigned u = __builtin_nontemporal_load(
          (const unsigned*)&base[(size_t)(gr0+row)*N_T + gc0 + c4*4]);
      NB[row*32 + c4] = (uint8_t)pk4(u);
    }
  } else {
    const i32x4* base = (const i32x4*)maskp;
    #pragma unroll
    for(int i=0;i<16;i++){
      int idx = i*256 + t;
      int row = idx >> 5, c4 = idx & 31;
      i32x4 v = __builtin_nontemporal_load(
          &base[((size_t)(gr0+row)*N_T + gc0) / 4 + c4]);
      NB[row*32 + c4] = (uint8_t)((unsigned)(v[0]!=0) | ((unsigned)(v[1]!=0)<<1)
                                | ((unsigned)(v[2]!=0)<<2) | ((unsigned)(v[3]!=0)<<3));
    }
  }
  __syncthreads();
  if(t < 128){
    uint4 a = *(const uint4*)&NB[t*32];
    uint4 b = *(const uint4*)&NB[t*32 + 16];
    unsigned w0 = nib8(a.x, a.y), w1 = nib8(a.z, a.w);
    unsigned w2 = nib8(b.x, b.y), w3 = nib8(b.z, b.w);
    MB[t*4]   = w0; MB[t*4+1] = w1;
    MB[t*4+2] = w2; MB[t*4+3] = w3;
    if(bitsOut){
      uint4 o; o.x=w0; o.y=w1; o.z=w2; o.w=w3;
      *(uint4*)&bitsOut[(size_t)(gr0 + t)*(N_T/32) + (gc0 >> 5)] = o;
    }
  }
}

// fp16 S^T GEMM core: A = et (M=target), B = eq (N=query). 128x128 tile, 4 waves.
// acc[m][n]: t_local = wr*64+m*16+kg0*4+reg, q_local = wc*64+n*16+fr
__device__ __forceinline__ void qk_gemm(
    const ushort* __restrict__ A16, const ushort* __restrict__ B16,
    int abase, int bbase, int t, ushort* SM, f32x4 (&acc)[4][4]){
  ushort* AB = SM;            // [128][64] swizzled
  ushort* BB = SM + 8192;
  int lane = t & 63;
  int w = t >> 6;
  int wr = w >> 1, wc = w & 1;
  int fr = lane & 15, kg0 = lane >> 4;
  for(int kt=0; kt<2; kt++){
    __syncthreads();
    #pragma unroll
    for(int it=0; it<4; it++){
      int idx = t + it*256;          // 0..1023
      int row = idx >> 3, k8 = idx & 7;
      int sw = (k8 ^ (row & 7)) * 8;
      *(uint4*)&AB[row*64 + sw] = *(const uint4*)&A16[(size_t)(abase+row)*H + kt*64 + k8*8];
      *(uint4*)&BB[row*64 + sw] = *(const uint4*)&B16[(size_t)(bbase+row)*H + kt*64 + k8*8];
    }
    __syncthreads();
    #pragma unroll
    for(int s=0; s<2; s++){
      int kg = s*4 + kg0;
      f16x8 a[4], b[4];
      #pragma unroll
      for(int m=0;m<4;m++){
        int ar = wr*64 + m*16 + fr;
        a[m] = *(const f16x8*)&AB[ar*64 + ((kg ^ (ar & 7)) << 3)];
      }
      #pragma unroll
      for(int n=0;n<4;n++){
        int bc = wc*64 + n*16 + fr;
        b[n] = *(const f16x8*)&BB[bc*64 + ((kg ^ (bc & 7)) << 3)];
      }
      #pragma unroll
      for(int m=0;m<4;m++)
        #pragma unroll
        for(int n=0;n<4;n++)
          acc[m][n] = __builtin_amdgcn_mfma_f32_16x16x32_f16(a[m], b[n], acc[m][n], 0,0,0);
    }
  }
}

// ---------------- attention pass A: raw mask -> bits, GEMM, rowsums ----------------
__global__ __launch_bounds__(256,4) void attsum_k(
    const ushort* __restrict__ eq16, const ushort* __restrict__ et16,
    const void* __restrict__ maskp, const int* __restrict__ flag,
    unsigned* __restrict__ bitsOut, float* __restrict__ rowsum){
  __shared__ ushort SM[2*128*64];       // 32 KB (first 4KB aliased as nibble staging)
  __shared__ __align__(16) unsigned MB[512];
  __shared__ float RS[128][2];
  int t = threadIdx.x;
  int gc0 = blockIdx.x * 128;   // target base
  int gr0 = blockIdx.y * 128;   // query base
  int lane = t & 63;
  int w = t >> 6;
  int wr = w >> 1, wc = w & 1;
  int fr = lane & 15, kg0 = lane >> 4;

  int mb = *flag;
  stage_mask_tile(maskp, mb, gr0, gc0, MB, (uint8_t*)SM, bitsOut, t);

  f32x4 acc[4][4] = {};
  qk_gemm(et16, eq16, gc0, gr0, t, SM, acc);

  const float sc = 0.08838834764831845f;   // 1/sqrt(128)
  #pragma unroll
  for(int n=0;n<4;n++){
    int q = wc*64 + n*16 + fr;
    float s = 0.f;
    #pragma unroll
    for(int m=0;m<4;m++){
      unsigned wb = MB[q*4 + wr*2 + (m>>1)];
      int off = ((m&1)<<4) | (kg0<<2);
      s += ((wb>>(off+0))&1u) ? __expf(acc[m][n][0]*sc) : 0.f;
      s += ((wb>>(off+1))&1u) ? __expf(acc[m][n][1]*sc) : 0.f;
      s += ((wb>>(off+2))&1u) ? __expf(acc[m][n][2]*sc) : 0.f;
      s += ((wb>>(off+3))&1u) ? __expf(acc[m][n][3]*sc) : 0.f;
    }
    s += __shfl_xor(s, 16);
    s += __shfl_xor(s, 32);
    if(lane < 16) RS[q][wr] = s;
  }
  __syncthreads();
  if(t < 128) atomicAdd(&rowsum[gr0 + t], RS[t][0] + RS[t][1]);
}

// ---------------- attention pass B: recompute, normalize, NT float4 store ----------------
__global__ __launch_bounds__(256,4) void attout_k(
    const ushort* __restrict__ eq16, const ushort* __restrict__ et16,
    const void* __restrict__ maskp, const int* __restrict__ flag,
    const unsigned* __restrict__ bitsIn, const float* __restrict__ rowsum,
    float* __restrict__ out){
  __shared__ ushort SM[2*128*64];
  __shared__ __align__(16) unsigned MB[512];
  __shared__ float IRS[128];
  int t = threadIdx.x;
  int gc0 = blockIdx.x * 128;
  int gr0 = blockIdx.y * 128;
  int lane = t & 63;
  int w = t >> 6;
  int wr = w >> 1, wc = w & 1;
  int fr = lane & 15, kg0 = lane >> 4;

  if(bitsIn){
    if(t < 128)
      *(uint4*)&MB[t*4] = *(const uint4*)&bitsIn[(size_t)(gr0 + t)*(N_T/32) + (gc0 >> 5)];
  } else {
    int mb = *flag;
    stage_mask_tile(maskp, mb, gr0, gc0, MB, (uint8_t*)SM, nullptr, t);
  }
  if(t < 128) IRS[t] = 1.0f / rowsum[gr0 + t];

  f32x4 acc[4][4] = {};
  qk_gemm(et16, eq16, gc0, gr0, t, SM, acc);

  const float sc = 0.08838834764831845f;
  #pragma unroll
  for(int n=0;n<4;n++){
    int q = wc*64 + n*16 + fr;
    float ir = IRS[q];
    size_t rb = (size_t)(gr0 + q)*N_T + gc0 + wr*64;
    #pragma unroll
    for(int m=0;m<4;m++){
      unsigned wb = MB[q*4 + wr*2 + (m>>1)];
      int off = ((m&1)<<4) | (kg0<<2);
      f32x4 o;
      o[0] = ((wb>>(off+0))&1u) ? __expf(acc[m][n][0]*sc)*ir : 0.f;
      o[1] = ((wb>>(off+1))&1u) ? __expf(acc[m][n][1]*sc)*ir : 0.f;
      o[2] = ((wb>>(off+2))&1u) ? __expf(acc[m][n][2]*sc)*ir : 0.f;
      o[3] = ((wb>>(off+3))&1u) ? __expf(acc[m][n][3]*sc)*ir : 0.f;
      __builtin_nontemporal_store(o, (f32x4*)&out[rb + m*16 + (kg0<<2)]);
    }
  }
}

// ---------------- host launch ----------------
extern "C" void kernel_launch(void* const* d_in, const int* in_sizes, int n_in,
                              void* d_out, int out_size, void* d_ws, size_t ws_size,
                              hipStream_t stream){
  const int* tx  = (const int*)d_in[0];
  const int* qx  = (const int*)d_in[1];
  const int* te  = (const int*)d_in[2];
  const int* qe  = (const int*)d_in[3];
  const void* mask = d_in[4];
  const float* emb = (const float*)d_in[5];
  const float* Wl  = (const float*)d_in[6];
  const float* bl  = (const float*)d_in[7];
  const float* Wr  = (const float*)d_in[8];
  float* out = (float*)d_out;

  // ws layout: features @0, rowsum/flag @9MB, weights @10MB, emb16 @11MB, bits @19MB
  ushort* et16 = (ushort*)d_ws;                       // N_T*H (8 MB)
  ushort* eq16 = et16 + (size_t)N_T*H;                // N_Q*H (1 MB)
  float* rowsum = (float*)((char*)d_ws + ((size_t)9 << 20));
  int*   flag   = (int*)(rowsum + N_Q);
  ushort* WH  = (ushort*)((char*)d_ws + ((size_t)10 << 20));   // NL*128*256 (192 KB)
  ushort* WLo = WH + (size_t)NL*128*256;
  ushort* emb16 = (ushort*)((char*)d_ws + ((size_t)11 << 20)); // VOCAB*H fp16 (256 KB)
  bool useBits = ws_size >= ((size_t)37 << 20);
  unsigned* bits = useBits ? (unsigned*)((char*)d_ws + ((size_t)19 << 20)) : nullptr;

  // phase-1 scratch inside d_out (512MB; fully overwritten by attout at the end)
  char* S = (char*)d_out;
  ushort* xt0  = (ushort*)(S);                         // 8 MB (layer0 out)
  ushort* xt1  = (ushort*)(S + 8388608);               // 8 MB (layer1 out)
  ushort* aggt = (ushort*)(S + 16777216);              // 8 MB
  ushort* xq0  = (ushort*)(S + 25165824);              // 1 MB
  ushort* xq1  = (ushort*)(S + 26214400);              // 1 MB
  ushort* aggq = (ushort*)(S + 27262976);              // 1 MB
  int*   cnt_t = (int*)(S + 28311552);
  int*   rp_t  = cnt_t + N_T;
  int*   pos_t = rp_t + N_T + 1;
  int*   csr_t = pos_t + N_T;
  int*   cnt_q = csr_t + E_T;
  int*   rp_q  = cnt_q + N_Q;
  int*   pos_q = rp_q + N_Q + 1;
  int*   csr_q = pos_q + N_Q;

  zero_i32_k<<<(N_T+255)/256,256,0,stream>>>(cnt_t, N_T);
  zero_i32_k<<<(N_Q+255)/256,256,0,stream>>>(cnt_q, N_Q);
  zero_f32_k<<<(N_Q+255)/256,256,0,stream>>>(rowsum, N_Q);
  zero_i32_k<<<1,256,0,stream>>>(flag, 1);
  detect_mask_k<<<1,256,0,stream>>>((const unsigned*)mask, flag);
  wcvt_k<<<96,256,0,stream>>>(Wl, Wr, WH, WLo);
  ecvt_k<<<(VOCAB*H/8+255)/256,256,0,stream>>>(emb, emb16);

  count_k<<<E_T/256,256,0,stream>>>(te+E_T, E_T, cnt_t);
  scan_k<<<1,1024,0,stream>>>(cnt_t, N_T, rp_t, pos_t);
  fill_k<<<E_T/256,256,0,stream>>>(te, te+E_T, E_T, pos_t, csr_t);
  count_k<<<E_Q/256,256,0,stream>>>(qe+E_Q, E_Q, cnt_q);
  scan_k<<<1,1024,0,stream>>>(cnt_q, N_Q, rp_q, pos_q);
  fill_k<<<E_Q/256,256,0,stream>>>(qe, qe+E_Q, E_Q, pos_q, csr_q);

  ushort* outs_t[NL] = {xt0, xt1, et16};
  ushort* outs_q[NL] = {xq0, xq1, eq16};
  const ushort* cur_t = nullptr;
  const ushort* cur_q = nullptr;
  for(int l=0;l<NL;l++){
    const ushort* wh = WH  + (size_t)l*128*256;
    const ushort* wl = WLo + (size_t)l*128*256;
    const int* nidt = (l==0) ? tx : nullptr;
    const int* nidq = (l==0) ? qx : nullptr;
    agg_k<<<N_T/4,256,0,stream>>>(cur_t, nidt, emb16, rp_t, csr_t, aggt, N_T);
    layer_k<<<N_T/128,256,0,stream>>>(aggt, cur_t, nidt, emb16, wh, wl,
                                      bl+(size_t)l*H, outs_t[l]);
    agg_k<<<N_Q/4,256,0,stream>>>(cur_q, nidq, emb16, rp_q, csr_q, aggq, N_Q);
    layer_k<<<N_Q/128,256,0,stream>>>(aggq, cur_q, nidq, emb16, wh, wl,
                                      bl+(size_t)l*H, outs_q[l]);
    cur_t = outs_t[l];
    cur_q = outs_q[l];
  }

  attsum_k<<<dim3(N_T/128, N_Q/128),256,0,stream>>>(eq16, et16, mask, flag, bits, rowsum);
  attout_k<<<dim3(N_T/128, N_Q/128),256,0,stream>>>(eq16, et16, mask, flag, bits, rowsum, out);
}

// Round 10
// 645.468 us; speedup vs baseline: 2.9694x; 1.1016x over previous
//
#include <hip/hip_runtime.h>
#include <stdint.h>

#define N_T 32768
#define N_Q 4096
#define E_T 1048576
#define E_Q 131072
#define H   128
#define NL  3
#define VOCAB 1001

typedef float    f32x4 __attribute__((ext_vector_type(4)));
typedef int      i32x4 __attribute__((ext_vector_type(4)));
typedef _Float16 f16x8 __attribute__((ext_vector_type(8)));

__device__ __forceinline__ ushort f2h(float x){
  union{_Float16 h; ushort u;} c; c.h = (_Float16)x; return c.u;
}
__device__ __forceinline__ float h2f(unsigned u){
  union{ushort u; _Float16 h;} c; c.u = (ushort)u; return (float)c.h;
}

// ---------------- fused setup: zero cnt_t/cnt_q/rowsum + detect mask dtype ----------------
// blocks 0..127: cnt_t; 128..143: cnt_q; 144..159: rowsum; 160: flag+detect
__global__ void setup_k(int* cnt_t, int* cnt_q, float* rowsum, int* flag,
                        const unsigned* m){
  int b = blockIdx.x, t = threadIdx.x;
  if(b < 128){ cnt_t[b*256+t] = 0; }
  else if(b < 144){ cnt_q[(b-128)*256+t] = 0; }
  else if(b < 160){ rowsum[(b-144)*256+t] = 0.f; }
  else {
    if(t == 0) *flag = 0;
    __syncthreads();
    int f = 0;
    for(int j=t;j<4096;j+=256){
      unsigned v = m[j];
      if(v > 1u) f |= (v & 0xFEFEFEFEu) ? 2 : 1;
    }
    if(f) atomicOr(flag, f);
  }
}

// ---------------- fused convert: weights f32->fp16 hi/lo  +  emb table f32->fp16 ----------------
__global__ void cvt_k(const float* __restrict__ Wl, const float* __restrict__ Wr,
                      ushort* __restrict__ WH, ushort* __restrict__ WLo,
                      const float* __restrict__ emb, ushort* __restrict__ emb16){
  int b = blockIdx.x, t = threadIdx.x;
  if(b < 96){
    int i = b*256 + t;                 // NL*128*64 = 24576
    int k  = (i & 63) * 4;
    int c  = (i >> 6) & 127;
    int l  = i >> 13;
    const float* src = (k < 128)
        ? &Wl[((size_t)l*128 + c)*128 + k]
        : &Wr[((size_t)l*128 + c)*128 + (k-128)];
    float4 v = *(const float4*)src;
    ushort4 h, lo;
    h.x = f2h(v.x); lo.x = f2h(v.x - h2f(h.x));
    h.y = f2h(v.y); lo.y = f2h(v.y - h2f(h.y));
    h.z = f2h(v.z); lo.z = f2h(v.z - h2f(h.z));
    h.w = f2h(v.w); lo.w = f2h(v.w - h2f(h.w));
    size_t off = ((size_t)l*128 + c)*256 + k;
    *(ushort4*)&WH[off]  = h;
    *(ushort4*)&WLo[off] = lo;
  } else {
    int i = (b-96)*256 + t;            // VOCAB*H/8 = 16016
    if(i >= VOCAB*H/8) return;
    float4 v0 = ((const float4*)emb)[(size_t)i*2];
    float4 v1 = ((const float4*)emb)[(size_t)i*2 + 1];
    uint4 u;
    u.x = (unsigned)f2h(v0.x) | ((unsigned)f2h(v0.y)<<16);
    u.y = (unsigned)f2h(v0.z) | ((unsigned)f2h(v0.w)<<16);
    u.z = (unsigned)f2h(v1.x) | ((unsigned)f2h(v1.y)<<16);
    u.w = (unsigned)f2h(v1.z) | ((unsigned)f2h(v1.w)<<16);
    ((uint4*)emb16)[i] = u;
  }
}

// ---------------- CSR build (both graphs per launch) ----------------
__global__ void count2_k(const int* __restrict__ te, const int* __restrict__ qe,
                         int* cnt_t, int* cnt_q){
  int b = blockIdx.x;
  if(b < E_T/256){
    int i = b*256 + threadIdx.x;
    atomicAdd(&cnt_t[te[E_T + i]], 1);
  } else {
    int i = (b - E_T/256)*256 + threadIdx.x;
    atomicAdd(&cnt_q[qe[E_Q + i]], 1);
  }
}

__device__ __forceinline__ void scan_body(const int* cnt, int n, int* rp, int* pos){
  __shared__ int part[1024];
  int t = threadIdx.x;
  int chunk = (n + 1023) >> 10;
  int lo = t*chunk, hi = lo+chunk; if(hi>n) hi=n;
  int s = 0;
  for(int i=lo;i<hi;i++) s += cnt[i];
  part[t] = s;
  __syncthreads();
  for(int off=1; off<1024; off<<=1){
    int v = (t >= off) ? part[t-off] : 0;
    __syncthreads();
    part[t] += v;
    __syncthreads();
  }
  int run = (t==0) ? 0 : part[t-1];
  for(int i=lo;i<hi;i++){ rp[i]=run; pos[i]=run; run += cnt[i]; }
  if(t==0) rp[n] = part[1023];
}

__global__ void scan2_k(const int* cnt_t, int* rp_t, int* pos_t,
                        const int* cnt_q, int* rp_q, int* pos_q){
  if(blockIdx.x == 0) scan_body(cnt_t, N_T, rp_t, pos_t);
  else                scan_body(cnt_q, N_Q, rp_q, pos_q);
}

__global__ void fill2_k(const int* __restrict__ te, const int* __restrict__ qe,
                        int* pos_t, int* csr_t, int* pos_q, int* csr_q){
  int b = blockIdx.x;
  if(b < E_T/256){
    int i = b*256 + threadIdx.x;
    int p = atomicAdd(&pos_t[te[E_T + i]], 1);
    csr_t[p] = te[i];
  } else {
    int i = (b - E_T/256)*256 + threadIdx.x;
    int p = atomicAdd(&pos_q[qe[E_Q + i]], 1);
    csr_q[p] = qe[i];
  }
}

// ---------------- segment mean, both graphs (fp16 features; layer0 via emb16[nid]) ----------------
__device__ __forceinline__ void agg_body(const ushort* x, const int* nid,
    const ushort* emb16, const int* rp, const int* csr, ushort* agg,
    int wid, int lane){
  const unsigned* xw = (const unsigned*)x;
  const unsigned* ew = (const unsigned*)emb16;
  int rs = rp[wid], re = rp[wid+1];
  float px[8], py[8];
  #pragma unroll
  for(int q=0;q<8;q++){ px[q]=0.f; py[q]=0.f; }
  int j = rs;
  if(nid){
    for(; j+8 <= re; j+=8){
      #pragma unroll
      for(int q=0;q<8;q++){
        unsigned u = ew[(size_t)nid[csr[j+q]]*64 + lane];
        px[q] += h2f(u & 0xFFFFu); py[q] += h2f(u >> 16);
      }
    }
    for(; j < re; j++){
      unsigned u = ew[(size_t)nid[csr[j]]*64 + lane];
      px[0] += h2f(u & 0xFFFFu); py[0] += h2f(u >> 16);
    }
  } else {
    for(; j+8 <= re; j+=8){
      #pragma unroll
      for(int q=0;q<8;q++){
        unsigned u = xw[(size_t)csr[j+q]*64 + lane];
        px[q] += h2f(u & 0xFFFFu); py[q] += h2f(u >> 16);
      }
    }
    for(; j < re; j++){
      unsigned u = xw[(size_t)csr[j]*64 + lane];
      px[0] += h2f(u & 0xFFFFu); py[0] += h2f(u >> 16);
    }
  }
  float sx = ((px[0]+px[1]) + (px[2]+px[3])) + ((px[4]+px[5]) + (px[6]+px[7]));
  float sy = ((py[0]+py[1]) + (py[2]+py[3])) + ((py[4]+py[5]) + (py[6]+py[7]));
  int c = re - rs; if(c < 1) c = 1;
  float inv = 1.0f / (float)c;
  ((unsigned*)agg)[(size_t)wid*64 + lane] =
      (unsigned)f2h(sx*inv) | ((unsigned)f2h(sy*inv) << 16);
}

__global__ void agg2_k(const ushort* xt, const ushort* xq,
                       const int* nidt, const int* nidq, const ushort* emb16,
                       const int* rp_t, const int* csr_t,
                       const int* rp_q, const int* csr_q,
                       ushort* aggt, ushort* aggq){
  int b = blockIdx.x;
  int lane = threadIdx.x & 63;
  int wv = threadIdx.x >> 6;
  if(b < N_T/4){
    agg_body(xt, nidt, emb16, rp_t, csr_t, aggt, b*4 + wv, lane);
  } else {
    agg_body(xq, nidq, emb16, rp_q, csr_q, aggq, (b - N_T/4)*4 + wv, lane);
  }
}

// ---------------- layer GEMM (MFMA), both graphs: out = elu([agg|x] @ [Wl|Wr]^T + bl) ----------------
__global__ __launch_bounds__(256,3) void layer2_k(
    const ushort* __restrict__ aggT, const ushort* __restrict__ xT,
    const int* __restrict__ nidT, ushort* __restrict__ outT,
    const ushort* __restrict__ aggQ, const ushort* __restrict__ xQ,
    const int* __restrict__ nidQ, ushort* __restrict__ outQ,
    const ushort* __restrict__ emb16,
    const ushort* __restrict__ WH, const ushort* __restrict__ WLo,
    const float* __restrict__ bl){
  __shared__ ushort SM3[3*128*64];     // SA | SH | SL (48 KB); reused as LT
  ushort* SA = SM3;
  ushort* SH = SM3 + 8192;
  ushort* SL = SM3 + 16384;
  int bq = (int)blockIdx.x - (N_T/128);
  const ushort* agg   = (bq < 0) ? aggT : aggQ;
  const ushort* xprev = (bq < 0) ? xT   : xQ;
  const int*    nid   = (bq < 0) ? nidT : nidQ;
  ushort*       out16 = (bq < 0) ? outT : outQ;
  int r0g = ((bq < 0) ? (int)blockIdx.x : bq) * 128;
  int t = threadIdx.x;
  int lane = t & 63;
  int w = t >> 6;
  int wr = w >> 1, wc = w & 1;
  int fr = lane & 15, kg0 = lane >> 4;
  f32x4 acc[4][4] = {};
  for(int kt=0; kt<4; kt++){
    __syncthreads();
    int ko = (kt & 1) * 64;
    #pragma unroll
    for(int it=0; it<4; it++){
      int idx = t + it*256;            // 0..1023
      int row = idx >> 3, k8 = idx & 7;
      int sw = (k8 ^ (row & 7)) * 8;
      uint4 av;
      if(kt < 2){
        av = *(const uint4*)&agg[(size_t)(r0g+row)*H + ko + k8*8];
      } else if(nid){
        av = *(const uint4*)&emb16[(size_t)nid[r0g+row]*H + ko + k8*8];
      } else {
        av = *(const uint4*)&xprev[(size_t)(r0g+row)*H + ko + k8*8];
      }
      *(uint4*)&SA[row*64 + sw] = av;
      *(uint4*)&SH[row*64 + sw] = *(const uint4*)&WH[row*256 + kt*64 + k8*8];
      *(uint4*)&SL[row*64 + sw] = *(const uint4*)&WLo[row*256 + kt*64 + k8*8];
    }
    __syncthreads();
    #pragma unroll
    for(int s=0; s<2; s++){
      int kg = s*4 + kg0;
      f16x8 a[4], bh[4], blo[4];
      #pragma unroll
      for(int m=0;m<4;m++){
        int ar = wr*64 + m*16 + fr;
        a[m] = *(const f16x8*)&SA[ar*64 + ((kg ^ (ar & 7)) << 3)];
      }
      #pragma unroll
      for(int n=0;n<4;n++){
        int bc = wc*64 + n*16 + fr;
        int ib = bc*64 + ((kg ^ (bc & 7)) << 3);
        bh[n]  = *(const f16x8*)&SH[ib];
        blo[n] = *(const f16x8*)&SL[ib];
      }
      #pragma unroll
      for(int m=0;m<4;m++)
        #pragma unroll
        for(int n=0;n<4;n++){
          acc[m][n] = __builtin_amdgcn_mfma_f32_16x16x32_f16(a[m], bh[n],  acc[m][n], 0,0,0);
          acc[m][n] = __builtin_amdgcn_mfma_f32_16x16x32_f16(a[m], blo[n], acc[m][n], 0,0,0);
        }
    }
  }
  __syncthreads();
  ushort* LT = SM3;                    // 128*128 ushort = 32 KB
  #pragma unroll
  for(int n=0;n<4;n++){
    int c = wc*64 + n*16 + fr;
    float b = bl[c];
    #pragma unroll
    for(int m=0;m<4;m++){
      int r = wr*64 + m*16 + kg0*4;
      #pragma unroll
      for(int reg=0;reg<4;reg++){
        float v = acc[m][n][reg] + b;
        v = (v > 0.f) ? v : expm1f(v);
        LT[(r+reg)*128 + c] = f2h(v);
      }
    }
  }
  __syncthreads();
  #pragma unroll
  for(int i=0;i<8;i++){
    int idx = t + i*256;               // 0..2047
    int row = idx >> 4, c8 = idx & 15;
    *(uint4*)&out16[(size_t)(r0g+row)*H + c8*8] = *(uint4*)&LT[row*128 + c8*8];
  }
}

// ---------------- attention helpers ----------------
__device__ __forceinline__ unsigned nib8(unsigned x, unsigned y){
  unsigned r = (x & 0xFu) | ((x>>4)&0xF0u) | ((x>>8)&0xF00u) | ((x>>12)&0xF000u);
  unsigned s = (y & 0xFu) | ((y>>4)&0xF0u) | ((y>>8)&0xF00u) | ((y>>12)&0xF000u);
  return r | (s<<16);
}
__device__ __forceinline__ unsigned pk4(unsigned u){
  return ((u & 0xFFu)       ? 1u : 0u) | ((u & 0xFF00u)     ? 2u : 0u)
       | ((u & 0xFF0000u)   ? 4u : 0u) | ((u & 0xFF000000u) ? 8u : 0u);
}

// stage 128x128 raw mask tile -> MB[512] packed bits (coalesced, NT loads, no ballot).
__device__ __forceinline__ void stage_mask_tile(const void* maskp, int mb,
    int gr0, int gc0, unsigned* MB, uint8_t* NB, unsigned* bitsOut, int t){
  if(mb & 2){
    const f32x4* base = (const f32x4*)maskp;
    #pragma unroll
    for(int i=0;i<16;i++){
      int idx = i*256 + t;
      int row = idx >> 5, c4 = idx & 31;
      f32x4 v = __builtin_nontemporal_load(
          &base[((size_t)(gr0+row)*N_T + gc0) / 4 + c4]);
      NB[row*32 + c4] = (uint8_t)((unsigned)(v[0]!=0.f) | ((unsigned)(v[1]!=0.f)<<1)
                                | ((unsigned)(v[2]!=0.f)<<2) | ((unsigned)(v[3]!=0.f)<<3));
    }
  } else if(mb & 1){
    const uint8_t* base = (const uint8_t*)maskp;
    #pragma unroll
    for(int i=0;i<16;i++){
      int idx = i*256 + t;
      int row = idx >> 5, c4 = idx & 31;
      unsigned u = __builtin_nontemporal_load(
          (const unsigned*)&base[(size_t)(gr0+row)*N_T + gc0 + c4*4]);
      NB[row*32 + c4] = (uint8_t)pk4(u);
    }
  } else {
    const i32x4* base = (const i32x4*)maskp;
    #pragma unroll
    for(int i=0;i<16;i++){
      int idx = i*256 + t;
      int row = idx >> 5, c4 = idx & 31;
      i32x4 v = __builtin_nontemporal_load(
          &base[((size_t)(gr0+row)*N_T + gc0) / 4 + c4]);
      NB[row*32 + c4] = (uint8_t)((unsigned)(v[0]!=0) | ((unsigned)(v[1]!=0)<<1)
                                | ((unsigned)(v[2]!=0)<<2) | ((unsigned)(v[3]!=0)<<3));
    }
  }
  __syncthreads();
  if(t < 128){
    uint4 a = *(const uint4*)&NB[t*32];
    uint4 b = *(const uint4*)&NB[t*32 + 16];
    unsigned w0 = nib8(a.x, a.y), w1 = nib8(a.z, a.w);
    unsigned w2 = nib8(b.x, b.y), w3 = nib8(b.z, b.w);
    MB[t*4]   = w0; MB[t*4+1] = w1;
    MB[t*4+2] = w2; MB[t*4+3] = w3;
    if(bitsOut){
      uint4 o; o.x=w0; o.y=w1; o.z=w2; o.w=w3;
      *(uint4*)&bitsOut[(size_t)(gr0 + t)*(N_T/32) + (gc0 >> 5)] = o;
    }
  }
}

// XCD-aware tile decode: each XCD owns a 32-tile et column panel (1 MB, L2-fit)
__device__ __forceinline__ void att_tile(int bid, int& gc0, int& gr0){
  int xcd = bid & 7;
  int idx = bid >> 3;
  gc0 = (xcd*32 + (idx & 31)) * 128;
  gr0 = (idx >> 5) * 128;
}

// fp16 S^T GEMM core: A = et (M=target), B = eq (N=query). 128x128 tile, 4 waves.
__device__ __forceinline__ void qk_gemm(
    const ushort* __restrict__ A16, const ushort* __restrict__ B16,
    int abase, int bbase, int t, ushort* SM, f32x4 (&acc)[4][4]){
  ushort* AB = SM;            // [128][64] swizzled
  ushort* BB = SM + 8192;
  int lane = t & 63;
  int w = t >> 6;
  int wr = w >> 1, wc = w & 1;
  int fr = lane & 15, kg0 = lane >> 4;
  for(int kt=0; kt<2; kt++){
    __syncthreads();
    #pragma unroll
    for(int it=0; it<4; it++){
      int idx = t + it*256;          // 0..1023
      int row = idx >> 3, k8 = idx & 7;
      int sw = (k8 ^ (row & 7)) * 8;
      *(uint4*)&AB[row*64 + sw] = *(const uint4*)&A16[(size_t)(abase+row)*H + kt*64 + k8*8];
      *(uint4*)&BB[row*64 + sw] = *(const uint4*)&B16[(size_t)(bbase+row)*H + kt*64 + k8*8];
    }
    __syncthreads();
    #pragma unroll
    for(int s=0; s<2; s++){
      int kg = s*4 + kg0;
      f16x8 a[4], b[4];
      #pragma unroll
      for(int m=0;m<4;m++){
        int ar = wr*64 + m*16 + fr;
        a[m] = *(const f16x8*)&AB[ar*64 + ((kg ^ (ar & 7)) << 3)];
      }
      #pragma unroll
      for(int n=0;n<4;n++){
        int bc = wc*64 + n*16 + fr;
        b[n] = *(const f16x8*)&BB[bc*64 + ((kg ^ (bc & 7)) << 3)];
      }
      #pragma unroll
      for(int m=0;m<4;m++)
        #pragma unroll
        for(int n=0;n<4;n++)
          acc[m][n] = __builtin_amdgcn_mfma_f32_16x16x32_f16(a[m], b[n], acc[m][n], 0,0,0);
    }
  }
}

// ---------------- attention pass A: raw mask -> bits, GEMM, rowsums ----------------
__global__ __launch_bounds__(256,4) void attsum_k(
    const ushort* __restrict__ eq16, const ushort* __restrict__ et16,
    const void* __restrict__ maskp, const int* __restrict__ flag,
    unsigned* __restrict__ bitsOut, float* __restrict__ rowsum){
  __shared__ ushort SM[2*128*64];       // 32 KB (first 4KB aliased as nibble staging)
  __shared__ __align__(16) unsigned MB[512];
  __shared__ float RS[128][2];
  int t = threadIdx.x;
  int gc0, gr0;
  att_tile(blockIdx.x, gc0, gr0);
  int lane = t & 63;
  int w = t >> 6;
  int wr = w >> 1, wc = w & 1;
  int fr = lane & 15, kg0 = lane >> 4;

  int mb = *flag;
  stage_mask_tile(maskp, mb, gr0, gc0, MB, (uint8_t*)SM, bitsOut, t);

  f32x4 acc[4][4] = {};
  qk_gemm(et16, eq16, gc0, gr0, t, SM, acc);

  const float sc = 0.08838834764831845f;   // 1/sqrt(128)
  #pragma unroll
  for(int n=0;n<4;n++){
    int q = wc*64 + n*16 + fr;
    float s = 0.f;
    #pragma unroll
    for(int m=0;m<4;m++){
      unsigned wb = MB[q*4 + wr*2 + (m>>1)];
      int off = ((m&1)<<4) | (kg0<<2);
      s += ((wb>>(off+0))&1u) ? __expf(acc[m][n][0]*sc) : 0.f;
      s += ((wb>>(off+1))&1u) ? __expf(acc[m][n][1]*sc) : 0.f;
      s += ((wb>>(off+2))&1u) ? __expf(acc[m][n][2]*sc) : 0.f;
      s += ((wb>>(off+3))&1u) ? __expf(acc[m][n][3]*sc) : 0.f;
    }
    s += __shfl_xor(s, 16);
    s += __shfl_xor(s, 32);
    if(lane < 16) RS[q][wr] = s;
  }
  __syncthreads();
  if(t < 128) atomicAdd(&rowsum[gr0 + t], RS[t][0] + RS[t][1]);
}

// ---------------- attention pass B: recompute, normalize, NT float4 store ----------------
__global__ __launch_bounds__(256,4) void attout_k(
    const ushort* __restrict__ eq16, const ushort* __restrict__ et16,
    const void* __restrict__ maskp, const int* __restrict__ flag,
    const unsigned* __restrict__ bitsIn, const float* __restrict__ rowsum,
    float* __restrict__ out){
  __shared__ ushort SM[2*128*64];
  __shared__ __align__(16) unsigned MB[512];
  __shared__ float IRS[128];
  int t = threadIdx.x;
  int gc0, gr0;
  att_tile(blockIdx.x, gc0, gr0);
  int lane = t & 63;
  int w = t >> 6;
  int wr = w >> 1, wc = w & 1;
  int fr = lane & 15, kg0 = lane >> 4;

  if(bitsIn){
    if(t < 128)
      *(uint4*)&MB[t*4] = *(const uint4*)&bitsIn[(size_t)(gr0 + t)*(N_T/32) + (gc0 >> 5)];
  } else {
    int mb = *flag;
    stage_mask_tile(maskp, mb, gr0, gc0, MB, (uint8_t*)SM, nullptr, t);
  }
  if(t < 128) IRS[t] = 1.0f / rowsum[gr0 + t];

  f32x4 acc[4][4] = {};
  qk_gemm(et16, eq16, gc0, gr0, t, SM, acc);

  const float sc = 0.08838834764831845f;
  #pragma unroll
  for(int n=0;n<4;n++){
    int q = wc*64 + n*16 + fr;
    float ir = IRS[q];
    size_t rb = (size_t)(gr0 + q)*N_T + gc0 + wr*64;
    #pragma unroll
    for(int m=0;m<4;m++){
      unsigned wb = MB[q*4 + wr*2 + (m>>1)];
      int off = ((m&1)<<4) | (kg0<<2);
      f32x4 o;
      o[0] = ((wb>>(off+0))&1u) ? __expf(acc[m][n][0]*sc)*ir : 0.f;
      o[1] = ((wb>>(off+1))&1u) ? __expf(acc[m][n][1]*sc)*ir : 0.f;
      o[2] = ((wb>>(off+2))&1u) ? __expf(acc[m][n][2]*sc)*ir : 0.f;
      o[3] = ((wb>>(off+3))&1u) ? __expf(acc[m][n][3]*sc)*ir : 0.f;
      __builtin_nontemporal_store(o, (f32x4*)&out[rb + m*16 + (kg0<<2)]);
    }
  }
}

// ---------------- host launch ----------------
extern "C" void kernel_launch(void* const* d_in, const int* in_sizes, int n_in,
                              void* d_out, int out_size, void* d_ws, size_t ws_size,
                              hipStream_t stream){
  const int* tx  = (const int*)d_in[0];
  const int* qx  = (const int*)d_in[1];
  const int* te  = (const int*)d_in[2];
  const int* qe  = (const int*)d_in[3];
  const void* mask = d_in[4];
  const float* emb = (const float*)d_in[5];
  const float* Wl  = (const float*)d_in[6];
  const float* bl  = (const float*)d_in[7];
  const float* Wr  = (const float*)d_in[8];
  float* out = (float*)d_out;

  // ws layout: features @0, rowsum/flag @9MB, weights @10MB, emb16 @11MB, bits @19MB
  ushort* et16 = (ushort*)d_ws;                       // N_T*H (8 MB)
  ushort* eq16 = et16 + (size_t)N_T*H;                // N_Q*H (1 MB)
  float* rowsum = (float*)((char*)d_ws + ((size_t)9 << 20));
  int*   flag   = (int*)(rowsum + N_Q);
  ushort* WH  = (ushort*)((char*)d_ws + ((size_t)10 << 20));   // NL*128*256 (192 KB)
  ushort* WLo = WH + (size_t)NL*128*256;
  ushort* emb16 = (ushort*)((char*)d_ws + ((size_t)11 << 20)); // VOCAB*H fp16 (256 KB)
  bool useBits = ws_size >= ((size_t)37 << 20);
  unsigned* bits = useBits ? (unsigned*)((char*)d_ws + ((size_t)19 << 20)) : nullptr;

  // phase-1 scratch inside d_out (512MB; fully overwritten by attout at the end)
  char* S = (char*)d_out;
  ushort* xt0  = (ushort*)(S);                         // 8 MB (layer0 out)
  ushort* xt1  = (ushort*)(S + 8388608);               // 8 MB (layer1 out)
  ushort* aggt = (ushort*)(S + 16777216);              // 8 MB
  ushort* xq0  = (ushort*)(S + 25165824);              // 1 MB
  ushort* xq1  = (ushort*)(S + 26214400);              // 1 MB
  ushort* aggq = (ushort*)(S + 27262976);              // 1 MB
  int*   cnt_t = (int*)(S + 28311552);
  int*   rp_t  = cnt_t + N_T;
  int*   pos_t = rp_t + N_T + 1;
  int*   csr_t = pos_t + N_T;
  int*   cnt_q = csr_t + E_T;
  int*   rp_q  = cnt_q + N_Q;
  int*   pos_q = rp_q + N_Q + 1;
  int*   csr_q = pos_q + N_Q;

  setup_k<<<161,256,0,stream>>>(cnt_t, cnt_q, rowsum, flag, (const unsigned*)mask);
  cvt_k<<<159,256,0,stream>>>(Wl, Wr, WH, WLo, emb, emb16);
  count2_k<<<E_T/256 + E_Q/256,256,0,stream>>>(te, qe, cnt_t, cnt_q);
  scan2_k<<<2,1024,0,stream>>>(cnt_t, rp_t, pos_t, cnt_q, rp_q, pos_q);
  fill2_k<<<E_T/256 + E_Q/256,256,0,stream>>>(te, qe, pos_t, csr_t, pos_q, csr_q);

  ushort* outs_t[NL] = {xt0, xt1, et16};
  ushort* outs_q[NL] = {xq0, xq1, eq16};
  const ushort* cur_t = nullptr;
  const ushort* cur_q = nullptr;
  for(int l=0;l<NL;l++){
    const ushort* wh = WH  + (size_t)l*128*256;
    const ushort* wl = WLo + (size_t)l*128*256;
    const int* nidt = (l==0) ? tx : nullptr;
    const int* nidq = (l==0) ? qx : nullptr;
    agg2_k<<<N_T/4 + N_Q/4,256,0,stream>>>(cur_t, cur_q, nidt, nidq, emb16,
                                           rp_t, csr_t, rp_q, csr_q, aggt, aggq);
    layer2_k<<<N_T/128 + N_Q/128,256,0,stream>>>(aggt, cur_t, nidt, outs_t[l],
                                                 aggq, cur_q, nidq, outs_q[l],
                                                 emb16, wh, wl, bl+(size_t)l*H);
    cur_t = outs_t[l];
    cur_q = outs_q[l];
  }

  attsum_k<<<8192,256,0,stream>>>(eq16, et16, mask, flag, bits, rowsum);
  attout_k<<<8192,256,0,stream>>>(eq16, et16, mask, flag, bits, rowsum, out);
}